// Round 1
// baseline (1589.166 us; speedup 1.0000x reference)
//
#include <hip/hip_runtime.h>
#include <math.h>

#define TS 64
#define KS 16
#define LDP 68  // padded LDS row (68%32=4 -> max 2-way bank conflict, keeps 16B alignment)

// ---------------- block reduction helpers (1-D 256-thread blocks) ----------------
__device__ __forceinline__ float blockReduceSum256(float v, float* red) {
  #pragma unroll
  for (int o = 32; o; o >>= 1) v += __shfl_xor(v, o);
  int wid = threadIdx.x >> 6, lane = threadIdx.x & 63;
  if (lane == 0) red[wid] = v;
  __syncthreads();
  v = red[0] + red[1] + red[2] + red[3];
  __syncthreads();
  return v;
}
__device__ __forceinline__ float blockReduceMax256(float v, float* red) {
  #pragma unroll
  for (int o = 32; o; o >>= 1) v = fmaxf(v, __shfl_xor(v, o));
  int wid = threadIdx.x >> 6, lane = threadIdx.x & 63;
  if (lane == 0) red[wid] = v;
  __syncthreads();
  v = fmaxf(fmaxf(red[0], red[1]), fmaxf(red[2], red[3]));
  __syncthreads();
  return v;
}

// ---------------- generic tiled fp32 GEMM: C = A @ B^T (or A @ B) + bias ----------------
// AMODE 0: A[m][k] plain.  AMODE 1: logical A[m][k] = (m==0 ? 0 : A[(m-1)*lda+k] - aux[k])
// BTRANS true: B is (N,K) row-major (NT gemm). false: B is (K,N) row-major (NN gemm).
// ksChunk>0: split-K; blockIdx.z selects k-range, aZ=bZ=0, cZ=M*ldc, no bias/relu.
template <int AMODE, bool BTRANS, bool RELU, bool CAUSAL>
__global__ __launch_bounds__(256) void gemm_k(
    const float* __restrict__ A, const float* __restrict__ B,
    const float* __restrict__ bias, float* __restrict__ C,
    const float* __restrict__ aux,
    int M, int N, int K, int lda, int ldb, int ldc,
    long aZ, long bZ, long cZ, int ksChunk)
{
  if (CAUSAL && blockIdx.x > blockIdx.y) return;  // tile fully above diagonal
  A += (size_t)blockIdx.z * aZ;
  B += (size_t)blockIdx.z * bZ;
  C += (size_t)blockIdx.z * cZ;
  const int kBeg = (ksChunk > 0) ? (int)blockIdx.z * ksChunk : 0;
  const int kEnd = (ksChunk > 0) ? min(K, kBeg + ksChunk) : K;

  __shared__ float As[KS][LDP];
  __shared__ float Bs[KS][LDP];
  const int tx = threadIdx.x, ty = threadIdx.y;
  const int tid = ty * 16 + tx;
  const int m0 = blockIdx.y * TS, n0 = blockIdx.x * TS;

  float acc[4][4] = {};
  const int arow = tid >> 2, acol = (tid & 3) << 2;   // A/B-NT loader: 64 rows x 16 k
  const int bkr  = tid >> 4, bnc  = (tid & 15) << 2;  // B-NN loader: 16 k x 64 n
  const bool fastA = (AMODE == 0) && ((lda & 3) == 0);
  const bool fastB = ((ldb & 3) == 0);

  for (int k0 = kBeg; k0 < kEnd; k0 += KS) {
    // ---- stage A tile (transposed into As[k][m]) ----
    {
      const int gm = m0 + arow;
      if (fastA && (k0 + KS <= kEnd) && gm < M) {
        float4 av = *(const float4*)(A + (size_t)gm * lda + (k0 + acol));
        As[acol + 0][arow] = av.x; As[acol + 1][arow] = av.y;
        As[acol + 2][arow] = av.z; As[acol + 3][arow] = av.w;
      } else {
        #pragma unroll
        for (int c = 0; c < 4; ++c) {
          const int k = k0 + acol + c;
          float v = 0.f;
          if (gm < M && k < kEnd) {
            if (AMODE == 1) v = (gm == 0) ? 0.f : A[(size_t)(gm - 1) * lda + k] - aux[k];
            else            v = A[(size_t)gm * lda + k];
          }
          As[acol + c][arow] = v;
        }
      }
    }
    // ---- stage B tile into Bs[k][n] ----
    if (BTRANS) {
      const int gn = n0 + arow;
      if (fastB && (k0 + KS <= kEnd) && gn < N) {
        float4 bv = *(const float4*)(B + (size_t)gn * ldb + (k0 + acol));
        Bs[acol + 0][arow] = bv.x; Bs[acol + 1][arow] = bv.y;
        Bs[acol + 2][arow] = bv.z; Bs[acol + 3][arow] = bv.w;
      } else {
        #pragma unroll
        for (int c = 0; c < 4; ++c) {
          const int k = k0 + acol + c;
          Bs[acol + c][arow] = (gn < N && k < kEnd) ? B[(size_t)gn * ldb + k] : 0.f;
        }
      }
    } else {
      const int k = k0 + bkr, gn = n0 + bnc;
      if (fastB && k < kEnd && (gn + 3) < N) {
        *(float4*)&Bs[bkr][bnc] = *(const float4*)(B + (size_t)k * ldb + gn);
      } else {
        #pragma unroll
        for (int c = 0; c < 4; ++c)
          Bs[bkr][bnc + c] = (k < kEnd && (gn + c) < N) ? B[(size_t)k * ldb + gn + c] : 0.f;
      }
    }
    __syncthreads();

    #pragma unroll
    for (int kk = 0; kk < KS; ++kk) {
      float4 a = *(const float4*)&As[kk][ty << 2];
      float4 b = *(const float4*)&Bs[kk][tx << 2];
      acc[0][0] += a.x * b.x; acc[0][1] += a.x * b.y; acc[0][2] += a.x * b.z; acc[0][3] += a.x * b.w;
      acc[1][0] += a.y * b.x; acc[1][1] += a.y * b.y; acc[1][2] += a.y * b.z; acc[1][3] += a.y * b.w;
      acc[2][0] += a.z * b.x; acc[2][1] += a.z * b.y; acc[2][2] += a.z * b.z; acc[2][3] += a.z * b.w;
      acc[3][0] += a.w * b.x; acc[3][1] += a.w * b.y; acc[3][2] += a.w * b.z; acc[3][3] += a.w * b.w;
    }
    __syncthreads();
  }

  #pragma unroll
  for (int i = 0; i < 4; ++i) {
    const int gm = m0 + (ty << 2) + i;
    if (gm >= M) continue;
    #pragma unroll
    for (int j = 0; j < 4; ++j) {
      const int gn = n0 + (tx << 2) + j;
      if (gn >= N) continue;
      float v = acc[i][j];
      if (bias) v += bias[gn];
      if (RELU) v = fmaxf(v, 0.f);
      C[(size_t)gm * ldc + gn] = v;
    }
  }
}

// ---------------- small prep kernels ----------------
__global__ void prep_bias2(const float* __restrict__ one_hot, const float* __restrict__ W_obj,
                           const float* __restrict__ b_vm, float* __restrict__ bias2) {
  int d = blockIdx.x * 256 + threadIdx.x;
  if (d < 1024) {
    float s = 0.f;
    #pragma unroll
    for (int j = 0; j < 8; ++j) s += one_hot[j] * W_obj[d * 8 + j];
    bias2[d] = b_vm[d] + s;
  }
}

__global__ void prep_bias3(const float* __restrict__ b_vr, const float* __restrict__ tmpl,
                           float* __restrict__ bias3, int n) {
  int v = blockIdx.x * 256 + threadIdx.x;
  if (v < n) bias3[v] = b_vr[v] + tmpl[v];
}

// sum 4 split-K partials + bias2 + positional encoding -> x
__global__ __launch_bounds__(256) void reduce_pe(const float* __restrict__ part,
                                                 const float* __restrict__ bias2,
                                                 float* __restrict__ x) {
  const int t = blockIdx.x;
  const float PECOEF = -9.210340371976184f / 512.f;  // -ln(10000)/512
  const int p = t % 25;
  for (int d = threadIdx.x; d < 1024; d += 256) {
    float s = bias2[d];
    #pragma unroll
    for (int z = 0; z < 4; ++z) s += part[(size_t)z * 524288 + (size_t)t * 1024 + d];
    float arg = (float)p * expf((float)(d >> 1) * PECOEF);
    s += (d & 1) ? cosf(arg) : sinf(arg);
    x[(size_t)t * 1024 + d] = s;
  }
}

// row-wise softmax with ALIBI bias + causal mask, in place on scores[h][i][:]
__global__ __launch_bounds__(256) void softmax_alibi(float* __restrict__ scores) {
  const int i = blockIdx.x, h = blockIdx.y;
  float* row = scores + ((size_t)h * 512 + i) * 512;
  const int tid = threadIdx.x;
  const int len = i + 1;
  const float sl = exp2f(-2.f * (float)(h + 1));
  const int j0 = tid, j1 = tid + 256;
  float v0 = -INFINITY, v1 = -INFINITY;
  if (j0 < len) v0 = row[j0] * 0.0625f - sl * (float)((i - j0) / 25);
  if (j1 < len) v1 = row[j1] * 0.0625f - sl * (float)((i - j1) / 25);
  __shared__ float red[4];
  float m = blockReduceMax256(fmaxf(v0, v1), red);
  float e0 = (j0 < len) ? expf(v0 - m) : 0.f;
  float e1 = (j1 < len) ? expf(v1 - m) : 0.f;
  float s = blockReduceSum256(e0 + e1, red);
  float inv = 1.f / s;
  row[j0] = e0 * inv;   // zero beyond len (e=0) so PV gemm can read full row
  row[j1] = e1 * inv;
}

// x = LN(x + t) * g + b   (row length 1024, 256 threads x float4)
__global__ __launch_bounds__(256) void ln_residual(float* __restrict__ x, const float* __restrict__ t_,
                                                   const float* __restrict__ g, const float* __restrict__ b) {
  const int t = blockIdx.x, tid = threadIdx.x;
  float4 y = ((const float4*)(x + (size_t)t * 1024))[tid];
  float4 z = ((const float4*)(t_ + (size_t)t * 1024))[tid];
  y.x += z.x; y.y += z.y; y.z += z.z; y.w += z.w;
  __shared__ float red[4];
  float s = blockReduceSum256(y.x + y.y + y.z + y.w, red);
  const float m = s * (1.f / 1024.f);
  float dx = y.x - m, dy = y.y - m, dz = y.z - m, dw = y.w - m;
  float q = blockReduceSum256(dx * dx + dy * dy + dz * dz + dw * dw, red);
  const float rs = rsqrtf(q * (1.f / 1024.f) + 1e-5f);
  float4 gg = ((const float4*)g)[tid], bb = ((const float4*)b)[tid];
  float4 o;
  o.x = dx * rs * gg.x + bb.x;
  o.y = dy * rs * gg.y + bb.y;
  o.z = dz * rs * gg.z + bb.z;
  o.w = dw * rs * gg.w + bb.w;
  ((float4*)(x + (size_t)t * 1024))[tid] = o;
}

// ---------------- host-side launch ----------------
extern "C" void kernel_launch(void* const* d_in, const int* in_sizes, int n_in,
                              void* d_out, int out_size, void* d_ws, size_t ws_size,
                              hipStream_t stream) {
  const float* audio   = (const float*)d_in[0];
  const float* vertice = (const float*)d_in[1];
  const float* tmpl    = (const float*)d_in[2];
  const float* one_hot = (const float*)d_in[3];
  const float* W_af    = (const float*)d_in[4];
  const float* b_af    = (const float*)d_in[5];
  const float* W_vm    = (const float*)d_in[6];
  const float* b_vm    = (const float*)d_in[7];
  const float* W_obj   = (const float*)d_in[8];
  const float* Wqkv_sa = (const float*)d_in[9];
  const float* bqkv_sa = (const float*)d_in[10];
  const float* Wo_sa   = (const float*)d_in[11];
  const float* bo_sa   = (const float*)d_in[12];
  const float* Wqkv_ca = (const float*)d_in[13];
  const float* bqkv_ca = (const float*)d_in[14];
  const float* Wo_ca   = (const float*)d_in[15];
  const float* bo_ca   = (const float*)d_in[16];
  const float* W1      = (const float*)d_in[17];
  const float* b1      = (const float*)d_in[18];
  const float* W2      = (const float*)d_in[19];
  const float* b2      = (const float*)d_in[20];
  const float* g1      = (const float*)d_in[21];
  const float* be1     = (const float*)d_in[22];
  const float* g2      = (const float*)d_in[23];
  const float* be2     = (const float*)d_in[24];
  const float* g3      = (const float*)d_in[25];
  const float* be3     = (const float*)d_in[26];
  const float* W_vr    = (const float*)d_in[27];
  const float* b_vr    = (const float*)d_in[28];
  float* out = (float*)d_out;

  float* W = (float*)d_ws;
  float* hidden = W;                  // 512*1024
  float* x      = hidden + 524288;    // 512*1024
  float* qkv    = x + 524288;         // 512*3072
  float* ctx    = qkv + 1572864;      // 512*1024
  float* tmp    = ctx + 524288;       // 512*1024
  float* h1     = tmp + 524288;       // 512*2048
  float* scores = h1 + 1048576;       // 4*512*512
  float* part   = scores + 1048576;   // 4*512*1024
  float* bias2  = part + 2097152;     // 1024
  float* bias3  = bias2 + 1024;       // 15069

  dim3 tb(16, 16);

  // combined biases
  prep_bias2<<<4, 256, 0, stream>>>(one_hot, W_obj, b_vm, bias2);
  prep_bias3<<<(15069 + 255) / 256, 256, 0, stream>>>(b_vr, tmpl, bias3, 15069);

  // hidden = audio @ W_af^T + b_af         (512x1024, K=768)
  gemm_k<0, true, false, false><<<dim3(16, 8, 1), tb, 0, stream>>>(
      audio, W_af, b_af, hidden, nullptr, 512, 1024, 768, 768, 768, 1024, 0, 0, 0, 0);

  // vin partials: (vertice_shift) @ W_vm^T   (512x1024, K=15069), split-K x4
  gemm_k<1, true, false, false><<<dim3(16, 8, 4), tb, 0, stream>>>(
      vertice, W_vm, nullptr, part, tmpl, 512, 1024, 15069, 15069, 15069, 1024,
      0, 0, 524288, 3768);
  // x = sum(parts) + (b_vm + style) + PE
  reduce_pe<<<512, 256, 0, stream>>>(part, bias2, x);

  // ---- self attention ----
  gemm_k<0, true, false, false><<<dim3(48, 8, 1), tb, 0, stream>>>(
      x, Wqkv_sa, bqkv_sa, qkv, nullptr, 512, 3072, 1024, 1024, 1024, 3072, 0, 0, 0, 0);
  // scores[h] = q_h @ k_h^T  (causal tiles only)
  gemm_k<0, true, false, true><<<dim3(8, 8, 4), tb, 0, stream>>>(
      qkv, qkv + 1024, nullptr, scores, nullptr, 512, 512, 256, 3072, 3072, 512,
      256, 256, 262144, 0);
  softmax_alibi<<<dim3(512, 4), 256, 0, stream>>>(scores);
  // ctx[h] = attn_h @ v_h   (NN gemm)
  gemm_k<0, false, false, false><<<dim3(4, 8, 4), tb, 0, stream>>>(
      scores, qkv + 2048, nullptr, ctx, nullptr, 512, 256, 512, 512, 3072, 1024,
      262144, 256, 256, 0);
  // out proj
  gemm_k<0, true, false, false><<<dim3(16, 8, 1), tb, 0, stream>>>(
      ctx, Wo_sa, bo_sa, tmp, nullptr, 512, 1024, 1024, 1024, 1024, 1024, 0, 0, 0, 0);
  ln_residual<<<512, 256, 0, stream>>>(x, tmp, g1, be1);

  // ---- cross attention: mask == identity -> just V then O projection ----
  gemm_k<0, true, false, false><<<dim3(16, 8, 1), tb, 0, stream>>>(
      hidden, Wqkv_ca + (size_t)2048 * 1024, bqkv_ca + 2048, ctx, nullptr,
      512, 1024, 1024, 1024, 1024, 1024, 0, 0, 0, 0);
  gemm_k<0, true, false, false><<<dim3(16, 8, 1), tb, 0, stream>>>(
      ctx, Wo_ca, bo_ca, tmp, nullptr, 512, 1024, 1024, 1024, 1024, 1024, 0, 0, 0, 0);
  ln_residual<<<512, 256, 0, stream>>>(x, tmp, g2, be2);

  // ---- feed forward ----
  gemm_k<0, true, true, false><<<dim3(32, 8, 1), tb, 0, stream>>>(
      x, W1, b1, h1, nullptr, 512, 2048, 1024, 1024, 1024, 2048, 0, 0, 0, 0);
  gemm_k<0, true, false, false><<<dim3(16, 8, 1), tb, 0, stream>>>(
      h1, W2, b2, tmp, nullptr, 512, 1024, 2048, 2048, 2048, 1024, 0, 0, 0, 0);
  ln_residual<<<512, 256, 0, stream>>>(x, tmp, g3, be3);

  // ---- final projection: out = x @ W_vr^T + (b_vr + tmpl) ----
  gemm_k<0, true, false, false><<<dim3(236, 8, 1), tb, 0, stream>>>(
      x, W_vr, bias3, out, nullptr, 512, 15069, 1024, 1024, 1024, 15069, 0, 0, 0, 0);
}

// Round 2
// 1288.097 us; speedup vs baseline: 1.2337x; 1.2337x over previous
//
#include <hip/hip_runtime.h>
#include <math.h>

#define TS 64
#define KS 16
#define LDP 68   // padded LDS row for 64-tile gemm
#define NSPLIT 16

// ---------------- block reduction helpers (1-D 256-thread blocks) ----------------
__device__ __forceinline__ float blockReduceSum256(float v, float* red) {
  #pragma unroll
  for (int o = 32; o; o >>= 1) v += __shfl_xor(v, o);
  int wid = threadIdx.x >> 6, lane = threadIdx.x & 63;
  if (lane == 0) red[wid] = v;
  __syncthreads();
  v = red[0] + red[1] + red[2] + red[3];
  __syncthreads();
  return v;
}
__device__ __forceinline__ float blockReduceMax256(float v, float* red) {
  #pragma unroll
  for (int o = 32; o; o >>= 1) v = fmaxf(v, __shfl_xor(v, o));
  int wid = threadIdx.x >> 6, lane = threadIdx.x & 63;
  if (lane == 0) red[wid] = v;
  __syncthreads();
  v = fmaxf(fmaxf(red[0], red[1]), fmaxf(red[2], red[3]));
  __syncthreads();
  return v;
}

// ---------------- generic 64x64 tiled fp32 GEMM: C = A @ B(^T) + bias ----------------
// BTRANS true: B is (N,K) row-major (NT). false: B is (K,N) row-major (NN).
// ksChunk>0: split-K; blockIdx.z selects k-range; cZ strides the partial buffers.
template <bool BTRANS, bool RELU, bool CAUSAL>
__global__ __launch_bounds__(256) void gemm_k(
    const float* __restrict__ A, const float* __restrict__ B,
    const float* __restrict__ bias, float* __restrict__ C,
    int M, int N, int K, int lda, int ldb, int ldc,
    long aZ, long bZ, long cZ, int ksChunk)
{
  if (CAUSAL && blockIdx.x > blockIdx.y) return;  // tile fully above diagonal
  A += (size_t)blockIdx.z * aZ;
  B += (size_t)blockIdx.z * bZ;
  C += (size_t)blockIdx.z * cZ;
  const int kBeg = (ksChunk > 0) ? (int)blockIdx.z * ksChunk : 0;
  const int kEnd = (ksChunk > 0) ? min(K, kBeg + ksChunk) : K;

  __shared__ float As[KS][LDP];
  __shared__ float Bs[KS][LDP];
  const int tx = threadIdx.x, ty = threadIdx.y;
  const int tid = ty * 16 + tx;
  const int m0 = blockIdx.y * TS, n0 = blockIdx.x * TS;

  float acc[4][4] = {};
  const int arow = tid >> 2, acol = (tid & 3) << 2;   // NT loader: 64 rows x 16 k
  const int bkr  = tid >> 4, bnc  = (tid & 15) << 2;  // NN loader: 16 k x 64 n
  const bool fastA = ((lda & 3) == 0);
  const bool fastB = ((ldb & 3) == 0);

  for (int k0 = kBeg; k0 < kEnd; k0 += KS) {
    // ---- stage A tile (transposed into As[k][m]) ----
    {
      const int gm = m0 + arow;
      if (fastA && (k0 + KS <= kEnd) && gm < M) {
        float4 av = *(const float4*)(A + (size_t)gm * lda + (k0 + acol));
        As[acol + 0][arow] = av.x; As[acol + 1][arow] = av.y;
        As[acol + 2][arow] = av.z; As[acol + 3][arow] = av.w;
      } else {
        #pragma unroll
        for (int c = 0; c < 4; ++c) {
          const int k = k0 + acol + c;
          As[acol + c][arow] = (gm < M && k < kEnd) ? A[(size_t)gm * lda + k] : 0.f;
        }
      }
    }
    // ---- stage B tile into Bs[k][n] ----
    if (BTRANS) {
      const int gn = n0 + arow;
      if (fastB && (k0 + KS <= kEnd) && gn < N) {
        float4 bv = *(const float4*)(B + (size_t)gn * ldb + (k0 + acol));
        Bs[acol + 0][arow] = bv.x; Bs[acol + 1][arow] = bv.y;
        Bs[acol + 2][arow] = bv.z; Bs[acol + 3][arow] = bv.w;
      } else {
        #pragma unroll
        for (int c = 0; c < 4; ++c) {
          const int k = k0 + acol + c;
          Bs[acol + c][arow] = (gn < N && k < kEnd) ? B[(size_t)gn * ldb + k] : 0.f;
        }
      }
    } else {
      const int k = k0 + bkr, gn = n0 + bnc;
      if (fastB && k < kEnd && (gn + 3) < N) {
        *(float4*)&Bs[bkr][bnc] = *(const float4*)(B + (size_t)k * ldb + gn);
      } else {
        #pragma unroll
        for (int c = 0; c < 4; ++c)
          Bs[bkr][bnc + c] = (k < kEnd && (gn + c) < N) ? B[(size_t)k * ldb + gn + c] : 0.f;
      }
    }
    __syncthreads();

    #pragma unroll
    for (int kk = 0; kk < KS; ++kk) {
      float4 a = *(const float4*)&As[kk][ty << 2];
      float4 b = *(const float4*)&Bs[kk][tx << 2];
      acc[0][0] += a.x * b.x; acc[0][1] += a.x * b.y; acc[0][2] += a.x * b.z; acc[0][3] += a.x * b.w;
      acc[1][0] += a.y * b.x; acc[1][1] += a.y * b.y; acc[1][2] += a.y * b.z; acc[1][3] += a.y * b.w;
      acc[2][0] += a.z * b.x; acc[2][1] += a.z * b.y; acc[2][2] += a.z * b.z; acc[2][3] += a.z * b.w;
      acc[3][0] += a.w * b.x; acc[3][1] += a.w * b.y; acc[3][2] += a.w * b.z; acc[3][3] += a.w * b.w;
    }
    __syncthreads();
  }

  #pragma unroll
  for (int i = 0; i < 4; ++i) {
    const int gm = m0 + (ty << 2) + i;
    if (gm >= M) continue;
    #pragma unroll
    for (int j = 0; j < 4; ++j) {
      const int gn = n0 + (tx << 2) + j;
      if (gn >= N) continue;
      float v = acc[i][j];
      if (bias) v += bias[gn];
      if (RELU) v = fmaxf(v, 0.f);
      C[(size_t)gm * ldc + gn] = v;
    }
  }
}

// ---------------- 128x128 tile / 8x8 microtile fp32 NT GEMM ----------------
// Requirements: M % 128 == 0 (no M bounds), K % 16 == 0, lda/ldb % 4 == 0.
// N may be ragged (B rows and C cols bounds-checked).
template <bool RELU>
__global__ __launch_bounds__(256) void gemm128(
    const float* __restrict__ A, const float* __restrict__ B,
    const float* __restrict__ bias, float* __restrict__ C,
    int N, int K, int lda, int ldb, int ldc)
{
  __shared__ float As[16][132];
  __shared__ float Bs[16][132];
  const int tid = threadIdx.x;
  const int m0 = blockIdx.y * 128, n0 = blockIdx.x * 128;
  const int lr = tid >> 2;            // 0..63
  const int lc = (tid & 3) << 2;      // 0,4,8,12
  const int tx = tid & 15, ty = tid >> 4;

  float acc[8][8] = {};

  const float* pA0 = A + (size_t)(m0 + lr) * lda + lc;
  const float* pA1 = pA0 + (size_t)64 * lda;
  const int gn0 = n0 + lr, gn1 = gn0 + 64;
  const float* pB0 = B + (size_t)gn0 * ldb + lc;
  const float* pB1 = pB0 + (size_t)64 * ldb;
  const bool ok0 = gn0 < N, ok1 = gn1 < N;
  const float4 z4 = make_float4(0.f, 0.f, 0.f, 0.f);

  for (int k0 = 0; k0 < K; k0 += 16) {
    float4 a0 = *(const float4*)(pA0 + k0);
    float4 a1 = *(const float4*)(pA1 + k0);
    float4 b0 = ok0 ? *(const float4*)(pB0 + k0) : z4;
    float4 b1 = ok1 ? *(const float4*)(pB1 + k0) : z4;
    As[lc + 0][lr] = a0.x; As[lc + 1][lr] = a0.y; As[lc + 2][lr] = a0.z; As[lc + 3][lr] = a0.w;
    As[lc + 0][lr + 64] = a1.x; As[lc + 1][lr + 64] = a1.y; As[lc + 2][lr + 64] = a1.z; As[lc + 3][lr + 64] = a1.w;
    Bs[lc + 0][lr] = b0.x; Bs[lc + 1][lr] = b0.y; Bs[lc + 2][lr] = b0.z; Bs[lc + 3][lr] = b0.w;
    Bs[lc + 0][lr + 64] = b1.x; Bs[lc + 1][lr + 64] = b1.y; Bs[lc + 2][lr + 64] = b1.z; Bs[lc + 3][lr + 64] = b1.w;
    __syncthreads();
    #pragma unroll
    for (int kk = 0; kk < 16; ++kk) {
      float4 al = *(const float4*)&As[kk][ty << 2];
      float4 ah = *(const float4*)&As[kk][(ty << 2) + 64];
      float4 bl = *(const float4*)&Bs[kk][tx << 2];
      float4 bh = *(const float4*)&Bs[kk][(tx << 2) + 64];
      float av[8] = {al.x, al.y, al.z, al.w, ah.x, ah.y, ah.z, ah.w};
      float bv[8] = {bl.x, bl.y, bl.z, bl.w, bh.x, bh.y, bh.z, bh.w};
      #pragma unroll
      for (int i = 0; i < 8; ++i)
        #pragma unroll
        for (int j = 0; j < 8; ++j)
          acc[i][j] += av[i] * bv[j];
    }
    __syncthreads();
  }

  #pragma unroll
  for (int i = 0; i < 8; ++i) {
    const int gm = m0 + (ty << 2) + (i & 3) + ((i >> 2) << 6);
    #pragma unroll
    for (int j = 0; j < 8; ++j) {
      const int gn = n0 + (tx << 2) + (j & 3) + ((j >> 2) << 6);
      if (gn < N) {
        float v = acc[i][j];
        if (bias) v += bias[gn];
        if (RELU) v = fmaxf(v, 0.f);
        C[(size_t)gm * ldc + gn] = v;
      }
    }
  }
}

// ---------------- small prep kernels ----------------
// Ap[t][k] (stride 15072) = t==0 ? 0 : vertice[t-1][k] - tmpl[k]; zero-pad k>=15069
__global__ __launch_bounds__(256) void prep_vin(const float* __restrict__ vertice,
                                                const float* __restrict__ tmpl,
                                                float* __restrict__ Ap) {
  const int t = blockIdx.x;
  for (int k = threadIdx.x; k < 15072; k += 256) {
    float v = 0.f;
    if (t > 0 && k < 15069) v = vertice[(size_t)(t - 1) * 15069 + k] - tmpl[k];
    Ap[(size_t)t * 15072 + k] = v;
  }
}

__global__ void prep_bias2(const float* __restrict__ one_hot, const float* __restrict__ W_obj,
                           const float* __restrict__ b_vm, float* __restrict__ bias2) {
  int d = blockIdx.x * 256 + threadIdx.x;
  if (d < 1024) {
    float s = 0.f;
    #pragma unroll
    for (int j = 0; j < 8; ++j) s += one_hot[j] * W_obj[d * 8 + j];
    bias2[d] = b_vm[d] + s;
  }
}

__global__ void prep_bias3(const float* __restrict__ b_vr, const float* __restrict__ tmpl,
                           float* __restrict__ bias3, int n) {
  int v = blockIdx.x * 256 + threadIdx.x;
  if (v < n) bias3[v] = b_vr[v] + tmpl[v];
}

// sum NSPLIT split-K partials + bias2 + positional encoding -> x
__global__ __launch_bounds__(256) void reduce_pe(const float* __restrict__ part,
                                                 const float* __restrict__ bias2,
                                                 float* __restrict__ x) {
  const int t = blockIdx.x;
  const float PECOEF = -9.210340371976184f / 512.f;  // -ln(10000)/512
  const int p = t % 25;
  for (int d = threadIdx.x; d < 1024; d += 256) {
    float s = bias2[d];
    #pragma unroll
    for (int z = 0; z < NSPLIT; ++z) s += part[(size_t)z * 524288 + (size_t)t * 1024 + d];
    float arg = (float)p * expf((float)(d >> 1) * PECOEF);
    s += (d & 1) ? cosf(arg) : sinf(arg);
    x[(size_t)t * 1024 + d] = s;
  }
}

// row-wise softmax with ALIBI bias + causal mask, in place on scores[h][i][:]
__global__ __launch_bounds__(256) void softmax_alibi(float* __restrict__ scores) {
  const int i = blockIdx.x, h = blockIdx.y;
  float* row = scores + ((size_t)h * 512 + i) * 512;
  const int tid = threadIdx.x;
  const int len = i + 1;
  const float sl = exp2f(-2.f * (float)(h + 1));
  const int j0 = tid, j1 = tid + 256;
  float v0 = -INFINITY, v1 = -INFINITY;
  if (j0 < len) v0 = row[j0] * 0.0625f - sl * (float)((i - j0) / 25);
  if (j1 < len) v1 = row[j1] * 0.0625f - sl * (float)((i - j1) / 25);
  __shared__ float red[4];
  float m = blockReduceMax256(fmaxf(v0, v1), red);
  float e0 = (j0 < len) ? expf(v0 - m) : 0.f;
  float e1 = (j1 < len) ? expf(v1 - m) : 0.f;
  float s = blockReduceSum256(e0 + e1, red);
  float inv = 1.f / s;
  row[j0] = e0 * inv;   // zero beyond len so PV gemm can read full row
  row[j1] = e1 * inv;
}

// x = LN(x + t) * g + b   (row length 1024, 256 threads x float4)
__global__ __launch_bounds__(256) void ln_residual(float* __restrict__ x, const float* __restrict__ t_,
                                                   const float* __restrict__ g, const float* __restrict__ b) {
  const int t = blockIdx.x, tid = threadIdx.x;
  float4 y = ((const float4*)(x + (size_t)t * 1024))[tid];
  float4 z = ((const float4*)(t_ + (size_t)t * 1024))[tid];
  y.x += z.x; y.y += z.y; y.z += z.z; y.w += z.w;
  __shared__ float red[4];
  float s = blockReduceSum256(y.x + y.y + y.z + y.w, red);
  const float m = s * (1.f / 1024.f);
  float dx = y.x - m, dy = y.y - m, dz = y.z - m, dw = y.w - m;
  float q = blockReduceSum256(dx * dx + dy * dy + dz * dz + dw * dw, red);
  const float rs = rsqrtf(q * (1.f / 1024.f) + 1e-5f);
  float4 gg = ((const float4*)g)[tid], bb = ((const float4*)b)[tid];
  float4 o;
  o.x = dx * rs * gg.x + bb.x;
  o.y = dy * rs * gg.y + bb.y;
  o.z = dz * rs * gg.z + bb.z;
  o.w = dw * rs * gg.w + bb.w;
  ((float4*)(x + (size_t)t * 1024))[tid] = o;
}

// ---------------- host-side launch ----------------
extern "C" void kernel_launch(void* const* d_in, const int* in_sizes, int n_in,
                              void* d_out, int out_size, void* d_ws, size_t ws_size,
                              hipStream_t stream) {
  const float* audio   = (const float*)d_in[0];
  const float* vertice = (const float*)d_in[1];
  const float* tmpl    = (const float*)d_in[2];
  const float* one_hot = (const float*)d_in[3];
  const float* W_af    = (const float*)d_in[4];
  const float* b_af    = (const float*)d_in[5];
  const float* W_vm    = (const float*)d_in[6];
  const float* b_vm    = (const float*)d_in[7];
  const float* W_obj   = (const float*)d_in[8];
  const float* Wqkv_sa = (const float*)d_in[9];
  const float* bqkv_sa = (const float*)d_in[10];
  const float* Wo_sa   = (const float*)d_in[11];
  const float* bo_sa   = (const float*)d_in[12];
  const float* Wqkv_ca = (const float*)d_in[13];
  const float* bqkv_ca = (const float*)d_in[14];
  const float* Wo_ca   = (const float*)d_in[15];
  const float* bo_ca   = (const float*)d_in[16];
  const float* W1      = (const float*)d_in[17];
  const float* b1      = (const float*)d_in[18];
  const float* W2      = (const float*)d_in[19];
  const float* b2      = (const float*)d_in[20];
  const float* g1      = (const float*)d_in[21];
  const float* be1     = (const float*)d_in[22];
  const float* g2      = (const float*)d_in[23];
  const float* be2     = (const float*)d_in[24];
  const float* g3      = (const float*)d_in[25];
  const float* be3     = (const float*)d_in[26];
  const float* W_vr    = (const float*)d_in[27];
  const float* b_vr    = (const float*)d_in[28];
  float* out = (float*)d_out;

  // workspace layout (floats). part region is reused for qkv/scores/ctx/h1
  // after reduce_pe has consumed the partials. Total ~17.7M floats (~71 MB).
  float* W = (float*)d_ws;
  float* Ap     = W;                    // 512*15072      = 7,716,864
  float* part   = Ap + 7716864;         // 16*524288      = 8,388,608
  float* qkv    = part;                 //   1,572,864 (alias)
  float* scores = qkv + 1572864;        //   1,048,576 (alias)
  float* ctx    = scores + 1048576;     //     524,288 (alias)
  float* h1     = ctx + 524288;         //   1,048,576 (alias)
  float* hidden = part + 8388608;       // 524,288
  float* x      = hidden + 524288;      // 524,288
  float* tmp    = x + 524288;           // 524,288
  float* bias2  = tmp + 524288;         // 1024
  float* bias3  = bias2 + 1024;         // 15069

  dim3 tb(16, 16);

  // prep passes
  prep_bias2<<<4, 256, 0, stream>>>(one_hot, W_obj, b_vm, bias2);
  prep_bias3<<<(15069 + 255) / 256, 256, 0, stream>>>(b_vr, tmpl, bias3, 15069);
  prep_vin<<<512, 256, 0, stream>>>(vertice, tmpl, Ap);

  // hidden = audio @ W_af^T + b_af         (512x1024, K=768)
  gemm_k<true, false, false><<<dim3(16, 8, 1), tb, 0, stream>>>(
      audio, W_af, b_af, hidden, 512, 1024, 768, 768, 768, 1024, 0, 0, 0, 0);

  // vin partials: Ap @ W_vm^T   (512x1024, K=15069), split-K x16
  gemm_k<true, false, false><<<dim3(16, 8, NSPLIT), tb, 0, stream>>>(
      Ap, W_vm, nullptr, part, 512, 1024, 15069, 15072, 15069, 1024,
      0, 0, 524288, 942);
  // x = sum(parts) + (b_vm + style) + PE
  reduce_pe<<<512, 256, 0, stream>>>(part, bias2, x);

  // ---- self attention ----
  gemm_k<true, false, false><<<dim3(48, 8, 1), tb, 0, stream>>>(
      x, Wqkv_sa, bqkv_sa, qkv, 512, 3072, 1024, 1024, 1024, 3072, 0, 0, 0, 0);
  // scores[h] = q_h @ k_h^T  (causal tiles only)
  gemm_k<true, false, true><<<dim3(8, 8, 4), tb, 0, stream>>>(
      qkv, qkv + 1024, nullptr, scores, 512, 512, 256, 3072, 3072, 512,
      256, 256, 262144, 0);
  softmax_alibi<<<dim3(512, 4), 256, 0, stream>>>(scores);
  // ctx[h] = attn_h @ v_h   (NN gemm)
  gemm_k<false, false, false><<<dim3(4, 8, 4), tb, 0, stream>>>(
      scores, qkv + 2048, nullptr, ctx, 512, 256, 512, 512, 3072, 1024,
      262144, 256, 256, 0);
  // out proj
  gemm_k<true, false, false><<<dim3(16, 8, 1), tb, 0, stream>>>(
      ctx, Wo_sa, bo_sa, tmp, 512, 1024, 1024, 1024, 1024, 1024, 0, 0, 0, 0);
  ln_residual<<<512, 256, 0, stream>>>(x, tmp, g1, be1);

  // ---- cross attention: mask == identity -> just V then O projection ----
  gemm_k<true, false, false><<<dim3(16, 8, 1), tb, 0, stream>>>(
      hidden, Wqkv_ca + (size_t)2048 * 1024, bqkv_ca + 2048, ctx,
      512, 1024, 1024, 1024, 1024, 1024, 0, 0, 0, 0);
  gemm_k<true, false, false><<<dim3(16, 8, 1), tb, 0, stream>>>(
      ctx, Wo_ca, bo_ca, tmp, 512, 1024, 1024, 1024, 1024, 1024, 0, 0, 0, 0);
  ln_residual<<<512, 256, 0, stream>>>(x, tmp, g2, be2);

  // ---- feed forward ----
  gemm_k<true, true, false><<<dim3(32, 8, 1), tb, 0, stream>>>(
      x, W1, b1, h1, 512, 2048, 1024, 1024, 1024, 2048, 0, 0, 0, 0);
  gemm_k<true, false, false><<<dim3(16, 8, 1), tb, 0, stream>>>(
      h1, W2, b2, tmp, 512, 1024, 2048, 2048, 2048, 1024, 0, 0, 0, 0);
  ln_residual<<<512, 256, 0, stream>>>(x, tmp, g3, be3);

  // ---- final projection: out = x @ W_vr^T + (b_vr + tmpl) ----
  // 128x128 tiles, 8x8 microtile: M=512 (%128), K=1024 (%16), N ragged.
  gemm128<false><<<dim3(118, 4), 256, 0, stream>>>(
      x, W_vr, bias3, out, 15069, 1024, 1024, 1024, 15069);
}

// Round 3
// 1278.490 us; speedup vs baseline: 1.2430x; 1.0075x over previous
//
#include <hip/hip_runtime.h>
#include <math.h>

typedef __attribute__((ext_vector_type(8))) short short8;
typedef __attribute__((ext_vector_type(4))) float f32x4;

#define LDK 40      // padded LDS row (bf16 elems): 80B = 20 banks -> max 2-way conflict
#define NSPLIT 8    // split-K for the vin GEMM
#define KVIN 15104  // 15069 padded to multiple of 32

__device__ __forceinline__ unsigned short f2bf(float f) {
  unsigned u = __float_as_uint(f);
  return (unsigned short)((u + 0x7fffu + ((u >> 16) & 1u)) >> 16);  // RNE
}
__device__ __forceinline__ float bf2f(unsigned short h) {
  return __uint_as_float(((unsigned)h) << 16);
}

// ---------------- block reduction helpers (1-D 256-thread blocks) ----------------
__device__ __forceinline__ float blockReduceSum256(float v, float* red) {
  #pragma unroll
  for (int o = 32; o; o >>= 1) v += __shfl_xor(v, o);
  int wid = threadIdx.x >> 6, lane = threadIdx.x & 63;
  if (lane == 0) red[wid] = v;
  __syncthreads();
  v = red[0] + red[1] + red[2] + red[3];
  __syncthreads();
  return v;
}
__device__ __forceinline__ float blockReduceMax256(float v, float* red) {
  #pragma unroll
  for (int o = 32; o; o >>= 1) v = fmaxf(v, __shfl_xor(v, o));
  int wid = threadIdx.x >> 6, lane = threadIdx.x & 63;
  if (lane == 0) red[wid] = v;
  __syncthreads();
  v = fmaxf(fmaxf(red[0], red[1]), fmaxf(red[2], red[3]));
  __syncthreads();
  return v;
}

// ============ bf16 hi/lo 3-pass MFMA GEMM: C = A @ B^T (+bias) ============
// A: (M,K) fp32 row-major, M = 4*128 (grid.y=4, no M bounds), lda%4==0.
// B: (N,K) fp32 row-major, ldb%4==0, N ragged (guarded). K%32==0.
// ksChunk>0: split-K over blockIdx.z (ksChunk%32==0); C strided by cZ.
// Accuracy: a=ah+al, b=bh+bl; acc += ah*bh + al*bh + ah*bl (drops ~2^-17 term).
template <bool BIAS, bool RELU>
__global__ __launch_bounds__(256, 2) void mfma_nt(
    const float* __restrict__ A, const float* __restrict__ B,
    const float* __restrict__ bias, float* __restrict__ C,
    int N, int K, int lda, int ldb, int ldc, long cZ, int ksChunk)
{
  __shared__ short Ah[128 * LDK], Al[128 * LDK], Bh[128 * LDK], Bl[128 * LDK];
  const int tid = threadIdx.x;
  const int kBeg = ksChunk ? (int)blockIdx.z * ksChunk : 0;
  const int kEnd = ksChunk ? kBeg + ksChunk : K;
  C += (size_t)blockIdx.z * cZ;
  const int m0 = blockIdx.y * 128, n0 = blockIdx.x * 128;

  // staging: thread -> (row 0..127, k-half 0/16)
  const int srow = tid >> 1, skc = (tid & 1) << 4;
  const float* pa = A + (size_t)(m0 + srow) * lda + skc;
  const int gbn = n0 + srow;
  const float* pb = B + (size_t)gbn * ldb + skc;
  const bool bok = gbn < N;

  // wave decomposition: 4 waves in 2x2, each computes 64x64
  const int lane = tid & 63;
  const int wr = ((tid >> 7) & 1) << 6;
  const int wc = ((tid >> 6) & 1) << 6;
  const int fr = lane & 15, fq = lane >> 4;

  f32x4 acc[4][4] = {};
  float4 ra0, ra1, ra2, ra3, rb0, rb1, rb2, rb3;
  const float4 z4 = make_float4(0.f, 0.f, 0.f, 0.f);

  // preload first k-step
  ra0 = *(const float4*)(pa + kBeg);     ra1 = *(const float4*)(pa + kBeg + 4);
  ra2 = *(const float4*)(pa + kBeg + 8); ra3 = *(const float4*)(pa + kBeg + 12);
  rb0 = bok ? *(const float4*)(pb + kBeg) : z4;      rb1 = bok ? *(const float4*)(pb + kBeg + 4) : z4;
  rb2 = bok ? *(const float4*)(pb + kBeg + 8) : z4;  rb3 = bok ? *(const float4*)(pb + kBeg + 12) : z4;

  for (int k0 = kBeg; k0 < kEnd; k0 += 32) {
    // ---- convert current regs to hi/lo bf16 ----
    float va[16] = {ra0.x, ra0.y, ra0.z, ra0.w, ra1.x, ra1.y, ra1.z, ra1.w,
                    ra2.x, ra2.y, ra2.z, ra2.w, ra3.x, ra3.y, ra3.z, ra3.w};
    float vb[16] = {rb0.x, rb0.y, rb0.z, rb0.w, rb1.x, rb1.y, rb1.z, rb1.w,
                    rb2.x, rb2.y, rb2.z, rb2.w, rb3.x, rb3.y, rb3.z, rb3.w};
    short8 sha0, sla0, sha1, sla1, shb0, slb0, shb1, slb1;
    #pragma unroll
    for (int i = 0; i < 8; ++i) {
      unsigned short h;
      h = f2bf(va[i]);     sha0[i] = (short)h; sla0[i] = (short)f2bf(va[i]     - bf2f(h));
      h = f2bf(va[i + 8]); sha1[i] = (short)h; sla1[i] = (short)f2bf(va[i + 8] - bf2f(h));
      h = f2bf(vb[i]);     shb0[i] = (short)h; slb0[i] = (short)f2bf(vb[i]     - bf2f(h));
      h = f2bf(vb[i + 8]); shb1[i] = (short)h; slb1[i] = (short)f2bf(vb[i + 8] - bf2f(h));
    }
    __syncthreads();  // previous step's fragment reads complete
    const int wb = srow * LDK + skc;
    *(short8*)&Ah[wb] = sha0; *(short8*)&Ah[wb + 8] = sha1;
    *(short8*)&Al[wb] = sla0; *(short8*)&Al[wb + 8] = sla1;
    *(short8*)&Bh[wb] = shb0; *(short8*)&Bh[wb + 8] = shb1;
    *(short8*)&Bl[wb] = slb0; *(short8*)&Bl[wb + 8] = slb1;
    if (k0 + 32 < kEnd) {  // issue next-step global loads; latency hides under MFMA
      const int k = k0 + 32;
      ra0 = *(const float4*)(pa + k);     ra1 = *(const float4*)(pa + k + 4);
      ra2 = *(const float4*)(pa + k + 8); ra3 = *(const float4*)(pa + k + 12);
      rb0 = bok ? *(const float4*)(pb + k) : z4;      rb1 = bok ? *(const float4*)(pb + k + 4) : z4;
      rb2 = bok ? *(const float4*)(pb + k + 8) : z4;  rb3 = bok ? *(const float4*)(pb + k + 12) : z4;
    }
    __syncthreads();  // writes visible

    // ---- fragments + 48 MFMA per wave ----
    short8 fah[4], fal[4];
    #pragma unroll
    for (int f = 0; f < 4; ++f) {
      const int r = (wr + f * 16 + fr) * LDK + fq * 8;
      fah[f] = *(const short8*)&Ah[r];
      fal[f] = *(const short8*)&Al[r];
    }
    #pragma unroll
    for (int g = 0; g < 4; ++g) {
      const int r = (wc + g * 16 + fr) * LDK + fq * 8;
      short8 fbh = *(const short8*)&Bh[r];
      short8 fbl = *(const short8*)&Bl[r];
      #pragma unroll
      for (int f = 0; f < 4; ++f) {
        acc[f][g] = __builtin_amdgcn_mfma_f32_16x16x32_bf16(fah[f], fbh, acc[f][g], 0, 0, 0);
        acc[f][g] = __builtin_amdgcn_mfma_f32_16x16x32_bf16(fal[f], fbh, acc[f][g], 0, 0, 0);
        acc[f][g] = __builtin_amdgcn_mfma_f32_16x16x32_bf16(fah[f], fbl, acc[f][g], 0, 0, 0);
      }
    }
  }

  // ---- epilogue: C/D layout col=lane&15, row=(lane>>4)*4+reg ----
  #pragma unroll
  for (int f = 0; f < 4; ++f) {
    const int gm = m0 + wr + f * 16 + fq * 4;
    #pragma unroll
    for (int g = 0; g < 4; ++g) {
      const int gn = n0 + wc + g * 16 + fr;
      if (gn < N) {
        float* cp = C + (size_t)gm * ldc + gn;
        #pragma unroll
        for (int i = 0; i < 4; ++i) {
          float v = acc[f][g][i];
          if (BIAS) v += bias[gn];
          if (RELU) v = fmaxf(v, 0.f);
          cp[(size_t)i * ldc] = v;
        }
      }
    }
  }
}

// ---------------- fp32 64x64 GEMM (kept for attention scores / PV only) ----------------
#define TS 64
#define KS 16
#define LDP 68
template <bool BTRANS, bool RELU, bool CAUSAL>
__global__ __launch_bounds__(256) void gemm_k(
    const float* __restrict__ A, const float* __restrict__ B,
    const float* __restrict__ bias, float* __restrict__ C,
    int M, int N, int K, int lda, int ldb, int ldc,
    long aZ, long bZ, long cZ, int ksChunk)
{
  if (CAUSAL && blockIdx.x > blockIdx.y) return;
  A += (size_t)blockIdx.z * aZ;
  B += (size_t)blockIdx.z * bZ;
  C += (size_t)blockIdx.z * cZ;
  const int kBeg = (ksChunk > 0) ? (int)blockIdx.z * ksChunk : 0;
  const int kEnd = (ksChunk > 0) ? min(K, kBeg + ksChunk) : K;

  __shared__ float As[KS][LDP];
  __shared__ float Bs[KS][LDP];
  const int tx = threadIdx.x, ty = threadIdx.y;
  const int tid = ty * 16 + tx;
  const int m0 = blockIdx.y * TS, n0 = blockIdx.x * TS;

  float acc[4][4] = {};
  const int arow = tid >> 2, acol = (tid & 3) << 2;
  const int bkr  = tid >> 4, bnc  = (tid & 15) << 2;
  const bool fastA = ((lda & 3) == 0);
  const bool fastB = ((ldb & 3) == 0);

  for (int k0 = kBeg; k0 < kEnd; k0 += KS) {
    {
      const int gm = m0 + arow;
      if (fastA && (k0 + KS <= kEnd) && gm < M) {
        float4 av = *(const float4*)(A + (size_t)gm * lda + (k0 + acol));
        As[acol + 0][arow] = av.x; As[acol + 1][arow] = av.y;
        As[acol + 2][arow] = av.z; As[acol + 3][arow] = av.w;
      } else {
        #pragma unroll
        for (int c = 0; c < 4; ++c) {
          const int k = k0 + acol + c;
          As[acol + c][arow] = (gm < M && k < kEnd) ? A[(size_t)gm * lda + k] : 0.f;
        }
      }
    }
    if (BTRANS) {
      const int gn = n0 + arow;
      if (fastB && (k0 + KS <= kEnd) && gn < N) {
        float4 bv = *(const float4*)(B + (size_t)gn * ldb + (k0 + acol));
        Bs[acol + 0][arow] = bv.x; Bs[acol + 1][arow] = bv.y;
        Bs[acol + 2][arow] = bv.z; Bs[acol + 3][arow] = bv.w;
      } else {
        #pragma unroll
        for (int c = 0; c < 4; ++c) {
          const int k = k0 + acol + c;
          Bs[acol + c][arow] = (gn < N && k < kEnd) ? B[(size_t)gn * ldb + k] : 0.f;
        }
      }
    } else {
      const int k = k0 + bkr, gn = n0 + bnc;
      if (fastB && k < kEnd && (gn + 3) < N) {
        *(float4*)&Bs[bkr][bnc] = *(const float4*)(B + (size_t)k * ldb + gn);
      } else {
        #pragma unroll
        for (int c = 0; c < 4; ++c)
          Bs[bkr][bnc + c] = (k < kEnd && (gn + c) < N) ? B[(size_t)k * ldb + gn + c] : 0.f;
      }
    }
    __syncthreads();

    #pragma unroll
    for (int kk = 0; kk < KS; ++kk) {
      float4 a = *(const float4*)&As[kk][ty << 2];
      float4 b = *(const float4*)&Bs[kk][tx << 2];
      acc[0][0] += a.x * b.x; acc[0][1] += a.x * b.y; acc[0][2] += a.x * b.z; acc[0][3] += a.x * b.w;
      acc[1][0] += a.y * b.x; acc[1][1] += a.y * b.y; acc[1][2] += a.y * b.z; acc[1][3] += a.y * b.w;
      acc[2][0] += a.z * b.x; acc[2][1] += a.z * b.y; acc[2][2] += a.z * b.z; acc[2][3] += a.z * b.w;
      acc[3][0] += a.w * b.x; acc[3][1] += a.w * b.y; acc[3][2] += a.w * b.z; acc[3][3] += a.w * b.w;
    }
    __syncthreads();
  }

  #pragma unroll
  for (int i = 0; i < 4; ++i) {
    const int gm = m0 + (ty << 2) + i;
    if (gm >= M) continue;
    #pragma unroll
    for (int j = 0; j < 4; ++j) {
      const int gn = n0 + (tx << 2) + j;
      if (gn >= N) continue;
      float v = acc[i][j];
      if (bias) v += bias[gn];
      if (RELU) v = fmaxf(v, 0.f);
      C[(size_t)gm * ldc + gn] = v;
    }
  }
}

// ---------------- prep / pointwise kernels ----------------
__global__ __launch_bounds__(256) void prep_vin(const float* __restrict__ vertice,
                                                const float* __restrict__ tmpl,
                                                float* __restrict__ Ap) {
  const int t = blockIdx.x;
  for (int k = threadIdx.x; k < KVIN; k += 256) {
    float v = 0.f;
    if (t > 0 && k < 15069) v = vertice[(size_t)(t - 1) * 15069 + k] - tmpl[k];
    Ap[(size_t)t * KVIN + k] = v;
  }
}

// pad W_vm (1024 x 15069) -> (1024 x 15104), zero tail
__global__ __launch_bounds__(256) void prep_wvm(const float* __restrict__ Wvm,
                                                float* __restrict__ Wp) {
  const int r = blockIdx.x;
  for (int k = threadIdx.x; k < KVIN; k += 256)
    Wp[(size_t)r * KVIN + k] = (k < 15069) ? Wvm[(size_t)r * 15069 + k] : 0.f;
}

__global__ void prep_bias2(const float* __restrict__ one_hot, const float* __restrict__ W_obj,
                           const float* __restrict__ b_vm, float* __restrict__ bias2) {
  int d = blockIdx.x * 256 + threadIdx.x;
  if (d < 1024) {
    float s = 0.f;
    #pragma unroll
    for (int j = 0; j < 8; ++j) s += one_hot[j] * W_obj[d * 8 + j];
    bias2[d] = b_vm[d] + s;
  }
}

__global__ void prep_bias3(const float* __restrict__ b_vr, const float* __restrict__ tmpl,
                           float* __restrict__ bias3, int n) {
  int v = blockIdx.x * 256 + threadIdx.x;
  if (v < n) bias3[v] = b_vr[v] + tmpl[v];
}

// sum NSPLIT split-K partials + bias2 + positional encoding -> x
__global__ __launch_bounds__(256) void reduce_pe(const float* __restrict__ part,
                                                 const float* __restrict__ bias2,
                                                 float* __restrict__ x) {
  const int t = blockIdx.x;
  const float PECOEF = -9.210340371976184f / 512.f;  // -ln(10000)/512
  const int p = t % 25;
  for (int d = threadIdx.x; d < 1024; d += 256) {
    float s = bias2[d];
    #pragma unroll
    for (int z = 0; z < NSPLIT; ++z) s += part[(size_t)z * 524288 + (size_t)t * 1024 + d];
    float arg = (float)p * expf((float)(d >> 1) * PECOEF);
    s += (d & 1) ? cosf(arg) : sinf(arg);
    x[(size_t)t * 1024 + d] = s;
  }
}

// row-wise softmax with ALIBI bias + causal mask, in place on scores[h][i][:]
__global__ __launch_bounds__(256) void softmax_alibi(float* __restrict__ scores) {
  const int i = blockIdx.x, h = blockIdx.y;
  float* row = scores + ((size_t)h * 512 + i) * 512;
  const int tid = threadIdx.x;
  const int len = i + 1;
  const float sl = exp2f(-2.f * (float)(h + 1));
  const int j0 = tid, j1 = tid + 256;
  float v0 = -INFINITY, v1 = -INFINITY;
  if (j0 < len) v0 = row[j0] * 0.0625f - sl * (float)((i - j0) / 25);
  if (j1 < len) v1 = row[j1] * 0.0625f - sl * (float)((i - j1) / 25);
  __shared__ float red[4];
  float m = blockReduceMax256(fmaxf(v0, v1), red);
  float e0 = (j0 < len) ? expf(v0 - m) : 0.f;
  float e1 = (j1 < len) ? expf(v1 - m) : 0.f;
  float s = blockReduceSum256(e0 + e1, red);
  float inv = 1.f / s;
  row[j0] = e0 * inv;
  row[j1] = e1 * inv;
}

// x = LN(x + t) * g + b
__global__ __launch_bounds__(256) void ln_residual(float* __restrict__ x, const float* __restrict__ t_,
                                                   const float* __restrict__ g, const float* __restrict__ b) {
  const int t = blockIdx.x, tid = threadIdx.x;
  float4 y = ((const float4*)(x + (size_t)t * 1024))[tid];
  float4 z = ((const float4*)(t_ + (size_t)t * 1024))[tid];
  y.x += z.x; y.y += z.y; y.z += z.z; y.w += z.w;
  __shared__ float red[4];
  float s = blockReduceSum256(y.x + y.y + y.z + y.w, red);
  const float m = s * (1.f / 1024.f);
  float dx = y.x - m, dy = y.y - m, dz = y.z - m, dw = y.w - m;
  float q = blockReduceSum256(dx * dx + dy * dy + dz * dz + dw * dw, red);
  const float rs = rsqrtf(q * (1.f / 1024.f) + 1e-5f);
  float4 gg = ((const float4*)g)[tid], bb = ((const float4*)b)[tid];
  float4 o;
  o.x = dx * rs * gg.x + bb.x;
  o.y = dy * rs * gg.y + bb.y;
  o.z = dz * rs * gg.z + bb.z;
  o.w = dw * rs * gg.w + bb.w;
  ((float4*)(x + (size_t)t * 1024))[tid] = o;
}

// ---------------- host-side launch ----------------
extern "C" void kernel_launch(void* const* d_in, const int* in_sizes, int n_in,
                              void* d_out, int out_size, void* d_ws, size_t ws_size,
                              hipStream_t stream) {
  const float* audio   = (const float*)d_in[0];
  const float* vertice = (const float*)d_in[1];
  const float* tmpl    = (const float*)d_in[2];
  const float* one_hot = (const float*)d_in[3];
  const float* W_af    = (const float*)d_in[4];
  const float* b_af    = (const float*)d_in[5];
  const float* W_vm    = (const float*)d_in[6];
  const float* b_vm    = (const float*)d_in[7];
  const float* W_obj   = (const float*)d_in[8];
  const float* Wqkv_sa = (const float*)d_in[9];
  const float* bqkv_sa = (const float*)d_in[10];
  const float* Wo_sa   = (const float*)d_in[11];
  const float* bo_sa   = (const float*)d_in[12];
  const float* Wqkv_ca = (const float*)d_in[13];
  const float* bqkv_ca = (const float*)d_in[14];
  const float* Wo_ca   = (const float*)d_in[15];
  const float* bo_ca   = (const float*)d_in[16];
  const float* W1      = (const float*)d_in[17];
  const float* b1      = (const float*)d_in[18];
  const float* W2      = (const float*)d_in[19];
  const float* b2      = (const float*)d_in[20];
  const float* g1      = (const float*)d_in[21];
  const float* be1     = (const float*)d_in[22];
  const float* g2      = (const float*)d_in[23];
  const float* be2     = (const float*)d_in[24];
  const float* g3      = (const float*)d_in[25];
  const float* be3     = (const float*)d_in[26];
  const float* W_vr    = (const float*)d_in[27];
  const float* b_vr    = (const float*)d_in[28];
  float* out = (float*)d_out;

  // workspace (floats), ~113.8 MB total:
  float* W = (float*)d_ws;
  float* Ap     = W;                     // 512*15104  = 7,733,248
  float* Wvmp   = Ap + 7733248;          // 1024*15104 = 15,466,496
  float* part   = Wvmp + 15466496;       // 8*524288   = 4,194,304
  float* qkv    = part;                  //   1,572,864 (alias, used after reduce_pe)
  float* scores = qkv + 1572864;         //   1,048,576 (alias)
  float* ctx    = scores + 1048576;      //     524,288 (alias)
  float* h1     = ctx + 524288;          //   1,048,576 (alias)
  float* hidden = Wvmp;                  // alias: Wvmp dead after vin GEMM
  float* x      = part + 4194304;        // 524,288
  float* tmp    = x + 524288;            // 524,288
  float* bias2  = tmp + 524288;          // 1024
  float* bias3  = bias2 + 1024;          // 15069

  dim3 tb(16, 16);

  // prep
  prep_bias2<<<4, 256, 0, stream>>>(one_hot, W_obj, b_vm, bias2);
  prep_bias3<<<(15069 + 255) / 256, 256, 0, stream>>>(b_vr, tmpl, bias3, 15069);
  prep_vin<<<512, 256, 0, stream>>>(vertice, tmpl, Ap);
  prep_wvm<<<1024, 256, 0, stream>>>(W_vm, Wvmp);

  // vin partials: Ap @ Wvmp^T  (512x1024, K=15104), split-K x8
  mfma_nt<false, false><<<dim3(8, 4, NSPLIT), 256, 0, stream>>>(
      Ap, Wvmp, nullptr, part, 1024, KVIN, KVIN, KVIN, 1024, 524288, KVIN / NSPLIT);
  reduce_pe<<<512, 256, 0, stream>>>(part, bias2, x);

  // hidden = audio @ W_af^T + b_af  (runs after vin; writes over Wvmp region)
  mfma_nt<true, false><<<dim3(8, 4, 1), 256, 0, stream>>>(
      audio, W_af, b_af, hidden, 1024, 768, 768, 768, 1024, 0, 0);

  // ---- self attention ----
  mfma_nt<true, false><<<dim3(24, 4, 1), 256, 0, stream>>>(
      x, Wqkv_sa, bqkv_sa, qkv, 3072, 1024, 1024, 1024, 3072, 0, 0);
  gemm_k<true, false, true><<<dim3(8, 8, 4), tb, 0, stream>>>(
      qkv, qkv + 1024, nullptr, scores, 512, 512, 256, 3072, 3072, 512,
      256, 256, 262144, 0);
  softmax_alibi<<<dim3(512, 4), 256, 0, stream>>>(scores);
  gemm_k<false, false, false><<<dim3(4, 8, 4), tb, 0, stream>>>(
      scores, qkv + 2048, nullptr, ctx, 512, 256, 512, 512, 3072, 1024,
      262144, 256, 256, 0);
  mfma_nt<true, false><<<dim3(8, 4, 1), 256, 0, stream>>>(
      ctx, Wo_sa, bo_sa, tmp, 1024, 1024, 1024, 1024, 1024, 0, 0);
  ln_residual<<<512, 256, 0, stream>>>(x, tmp, g1, be1);

  // ---- cross attention: bool mask == identity -> V then O projection ----
  mfma_nt<true, false><<<dim3(8, 4, 1), 256, 0, stream>>>(
      hidden, Wqkv_ca + (size_t)2048 * 1024, bqkv_ca + 2048, ctx,
      1024, 1024, 1024, 1024, 1024, 0, 0);
  mfma_nt<true, false><<<dim3(8, 4, 1), 256, 0, stream>>>(
      ctx, Wo_ca, bo_ca, tmp, 1024, 1024, 1024, 1024, 1024, 0, 0);
  ln_residual<<<512, 256, 0, stream>>>(x, tmp, g2, be2);

  // ---- feed forward ----
  mfma_nt<true, true><<<dim3(16, 4, 1), 256, 0, stream>>>(
      x, W1, b1, h1, 2048, 1024, 1024, 1024, 2048, 0, 0);
  mfma_nt<true, false><<<dim3(8, 4, 1), 256, 0, stream>>>(
      h1, W2, b2, tmp, 1024, 2048, 2048, 2048, 1024, 0, 0);
  ln_residual<<<512, 256, 0, stream>>>(x, tmp, g3, be3);

  // ---- final projection: out = x @ W_vr^T + (b_vr + tmpl) ----
  mfma_nt<true, false><<<dim3(118, 4, 1), 256, 0, stream>>>(
      x, W_vr, bias3, out, 15069, 1024, 1024, 1024, 15069, 0, 0);
}

// Round 4
// 439.656 us; speedup vs baseline: 3.6146x; 2.9079x over previous
//
#include <hip/hip_runtime.h>
#include <math.h>

typedef __attribute__((ext_vector_type(8))) short short8;
typedef __attribute__((ext_vector_type(4))) float f32x4;
typedef unsigned short ushort_t;

#define LDK 40      // padded LDS row (bf16 elems): 80B stride -> max 2-way bank conflict (free)
#define KVIN 15104  // 15069 padded to multiple of 32

__device__ __forceinline__ ushort_t f2bf(float f) {
  unsigned u = __float_as_uint(f);
  return (ushort_t)((u + 0x7fffu + ((u >> 16) & 1u)) >> 16);  // RNE
}
__device__ __forceinline__ float bf2f(ushort_t h) {
  return __uint_as_float(((unsigned)h) << 16);
}

// ---------------- block reduction helpers (256-thread blocks) ----------------
__device__ __forceinline__ float blockReduceSum256(float v, float* red) {
  #pragma unroll
  for (int o = 32; o; o >>= 1) v += __shfl_xor(v, o);
  int wid = threadIdx.x >> 6, lane = threadIdx.x & 63;
  if (lane == 0) red[wid] = v;
  __syncthreads();
  v = red[0] + red[1] + red[2] + red[3];
  __syncthreads();
  return v;
}
__device__ __forceinline__ float blockReduceMax256(float v, float* red) {
  #pragma unroll
  for (int o = 32; o; o >>= 1) v = fmaxf(v, __shfl_xor(v, o));
  int wid = threadIdx.x >> 6, lane = threadIdx.x & 63;
  if (lane == 0) red[wid] = v;
  __syncthreads();
  v = fmaxf(fmaxf(red[0], red[1]), fmaxf(red[2], red[3]));
  __syncthreads();
  return v;
}

// ============ pre-split bf16 MFMA GEMM: C = A @ B^T (+bias) ============
// A,B given as bf16 hi/lo planes (ushort row-major). M = 512 (grid.y=4, exact).
// N ragged (guarded). k-range per block: kChunk ? [z*kChunk, z*kChunk+kChunk) : [0,K).
// A += z*aZ, B += z*bZ, C += z*cZ (element offsets) for batching (heads).
// PASSES==2: acc += Ah*Bh + Al*Bh (B hi only).  PASSES==3: + Ah*Bl.
template <int PASSES, bool BIAS, bool CAUSAL>
__global__ __launch_bounds__(256, 2) void gsplit(
    const ushort_t* __restrict__ Ah, const ushort_t* __restrict__ Al,
    const ushort_t* __restrict__ Bh, const ushort_t* __restrict__ Bl,
    const float* __restrict__ bias, float* __restrict__ C,
    int N, int K, int lda, int ldb, int ldc,
    int kChunk, long aZ, long bZ, long cZ)
{
  if (CAUSAL && blockIdx.x > blockIdx.y) return;
  __shared__ ushort_t sAh[128 * LDK], sAl[128 * LDK], sBh[128 * LDK], sBl[128 * LDK];
  const int tid = threadIdx.x, z = blockIdx.z;
  const int kBeg = kChunk ? z * kChunk : 0;
  const int kEnd = kChunk ? kBeg + kChunk : K;
  Ah += (size_t)z * aZ; Al += (size_t)z * aZ;
  Bh += (size_t)z * bZ; if (PASSES == 3) Bl += (size_t)z * bZ;
  C  += (size_t)z * cZ;
  const int m0 = blockIdx.y * 128, n0 = blockIdx.x * 128;

  // staging map: thread -> (row 0..127, k-half 0/16)
  const int srow = tid >> 1, skc = (tid & 1) << 4;
  const ushort_t* pAh = Ah + (size_t)(m0 + srow) * lda + skc;
  const ushort_t* pAl = Al + (size_t)(m0 + srow) * lda + skc;
  const int gbn = n0 + srow;
  const bool bok = gbn < N;
  const ushort_t* pBh = Bh + (size_t)gbn * ldb + skc;
  const ushort_t* pBl = (PASSES == 3) ? Bl + (size_t)gbn * ldb + skc : pBh;

  // waves: 2x2, each 64x64
  const int lane = tid & 63;
  const int wr = ((tid >> 7) & 1) << 6;
  const int wc = ((tid >> 6) & 1) << 6;
  const int fr = lane & 15, fq = lane >> 4;

  f32x4 acc[4][4] = {};
  const short8 z8 = {0, 0, 0, 0, 0, 0, 0, 0};
  short8 rah0, rah1, ral0, ral1, rbh0, rbh1, rbl0, rbl1;

  // preload first k-step
  rah0 = *(const short8*)(pAh + kBeg); rah1 = *(const short8*)(pAh + kBeg + 8);
  ral0 = *(const short8*)(pAl + kBeg); ral1 = *(const short8*)(pAl + kBeg + 8);
  rbh0 = bok ? *(const short8*)(pBh + kBeg) : z8;
  rbh1 = bok ? *(const short8*)(pBh + kBeg + 8) : z8;
  if (PASSES == 3) {
    rbl0 = bok ? *(const short8*)(pBl + kBeg) : z8;
    rbl1 = bok ? *(const short8*)(pBl + kBeg + 8) : z8;
  }

  for (int k0 = kBeg; k0 < kEnd; k0 += 32) {
    __syncthreads();  // prior iter's fragment reads complete
    const int wb = srow * LDK + skc;
    *(short8*)&sAh[wb] = rah0; *(short8*)&sAh[wb + 8] = rah1;
    *(short8*)&sAl[wb] = ral0; *(short8*)&sAl[wb + 8] = ral1;
    *(short8*)&sBh[wb] = rbh0; *(short8*)&sBh[wb + 8] = rbh1;
    if (PASSES == 3) { *(short8*)&sBl[wb] = rbl0; *(short8*)&sBl[wb + 8] = rbl1; }
    if (k0 + 32 < kEnd) {  // prefetch next k-step; latency hides under MFMA
      const int k = k0 + 32;
      rah0 = *(const short8*)(pAh + k); rah1 = *(const short8*)(pAh + k + 8);
      ral0 = *(const short8*)(pAl + k); ral1 = *(const short8*)(pAl + k + 8);
      rbh0 = bok ? *(const short8*)(pBh + k) : z8;
      rbh1 = bok ? *(const short8*)(pBh + k + 8) : z8;
      if (PASSES == 3) {
        rbl0 = bok ? *(const short8*)(pBl + k) : z8;
        rbl1 = bok ? *(const short8*)(pBl + k + 8) : z8;
      }
    }
    __syncthreads();  // writes visible

    short8 fah[4], fal[4];
    #pragma unroll
    for (int f = 0; f < 4; ++f) {
      const int r = (wr + f * 16 + fr) * LDK + fq * 8;
      fah[f] = *(const short8*)&sAh[r];
      fal[f] = *(const short8*)&sAl[r];
    }
    #pragma unroll
    for (int g = 0; g < 4; ++g) {
      const int r = (wc + g * 16 + fr) * LDK + fq * 8;
      short8 fbh = *(const short8*)&sBh[r];
      #pragma unroll
      for (int f = 0; f < 4; ++f) {
        acc[f][g] = __builtin_amdgcn_mfma_f32_16x16x32_bf16(fah[f], fbh, acc[f][g], 0, 0, 0);
        acc[f][g] = __builtin_amdgcn_mfma_f32_16x16x32_bf16(fal[f], fbh, acc[f][g], 0, 0, 0);
      }
      if (PASSES == 3) {
        short8 fbl = *(const short8*)&sBl[r];
        #pragma unroll
        for (int f = 0; f < 4; ++f)
          acc[f][g] = __builtin_amdgcn_mfma_f32_16x16x32_bf16(fah[f], fbl, acc[f][g], 0, 0, 0);
      }
    }
  }

  // epilogue: C/D layout col=lane&15, row=(lane>>4)*4+reg
  #pragma unroll
  for (int f = 0; f < 4; ++f) {
    const int gm = m0 + wr + f * 16 + fq * 4;
    #pragma unroll
    for (int g = 0; g < 4; ++g) {
      const int gn = n0 + wc + g * 16 + fr;
      if (gn < N) {
        float* cp = C + (size_t)gm * ldc + gn;
        #pragma unroll
        for (int i = 0; i < 4; ++i) {
          float v = acc[f][g][i];
          if (BIAS) v += bias[gn];
          cp[(size_t)i * ldc] = v;
        }
      }
    }
  }
}

// ---------------- split-K combine: out = sum_z part[z] + bias (+relu) ----------------
template <bool RELU, bool F32OUT, bool PLANES>
__global__ __launch_bounds__(256) void combine(
    const float* __restrict__ part, const float* __restrict__ bias,
    float* __restrict__ outf, ushort_t* __restrict__ outh, ushort_t* __restrict__ outl,
    int nz, long zstride, int total4, int N4)
{
  const int i = blockIdx.x * 256 + threadIdx.x;
  if (i >= total4) return;
  float4 s = ((const float4*)bias)[i % N4];
  for (int z = 0; z < nz; ++z) {
    float4 p = ((const float4*)(part + (size_t)z * zstride))[i];
    s.x += p.x; s.y += p.y; s.z += p.z; s.w += p.w;
  }
  if (RELU) {
    s.x = fmaxf(s.x, 0.f); s.y = fmaxf(s.y, 0.f);
    s.z = fmaxf(s.z, 0.f); s.w = fmaxf(s.w, 0.f);
  }
  if (F32OUT) ((float4*)outf)[i] = s;
  if (PLANES) {
    ushort_t h0 = f2bf(s.x), h1 = f2bf(s.y), h2 = f2bf(s.z), h3 = f2bf(s.w);
    ((ushort4*)outh)[i] = make_ushort4(h0, h1, h2, h3);
    ((ushort4*)outl)[i] = make_ushort4(f2bf(s.x - bf2f(h0)), f2bf(s.y - bf2f(h1)),
                                       f2bf(s.z - bf2f(h2)), f2bf(s.w - bf2f(h3)));
  }
}

// ---------------- fp32 (R x Csrc) -> hi(/lo) planes (R x Cdst), zero-padded ----------------
template <bool LO>
__global__ __launch_bounds__(256) void split_pad(
    const float* __restrict__ src, ushort_t* __restrict__ dh, ushort_t* __restrict__ dl,
    int Csrc, int Cdst)
{
  const int r = blockIdx.x;
  for (int c = threadIdx.x; c < Cdst; c += 256) {
    float v = (c < Csrc) ? src[(size_t)r * Csrc + c] : 0.f;
    ushort_t h = f2bf(v);
    dh[(size_t)r * Cdst + c] = h;
    if (LO) dl[(size_t)r * Cdst + c] = f2bf(v - bf2f(h));
  }
}

// ---------------- vin input: planes of concat(0, vertice[:-1]) - tmpl ----------------
__global__ __launch_bounds__(256) void prep_vin(const float* __restrict__ vertice,
                                                const float* __restrict__ tmpl,
                                                ushort_t* __restrict__ dh, ushort_t* __restrict__ dl) {
  const int t = blockIdx.x;
  for (int k = threadIdx.x; k < KVIN; k += 256) {
    float v = 0.f;
    if (t > 0 && k < 15069) v = vertice[(size_t)(t - 1) * 15069 + k] - tmpl[k];
    ushort_t h = f2bf(v);
    dh[(size_t)t * KVIN + k] = h;
    dl[(size_t)t * KVIN + k] = f2bf(v - bf2f(h));
  }
}

__global__ void prep_bias2(const float* __restrict__ one_hot, const float* __restrict__ W_obj,
                           const float* __restrict__ b_vm, float* __restrict__ bias2) {
  int d = blockIdx.x * 256 + threadIdx.x;
  if (d < 1024) {
    float s = 0.f;
    #pragma unroll
    for (int j = 0; j < 8; ++j) s += one_hot[j] * W_obj[d * 8 + j];
    bias2[d] = b_vm[d] + s;
  }
}

__global__ void prep_bias3(const float* __restrict__ b_vr, const float* __restrict__ tmpl,
                           float* __restrict__ bias3, int n) {
  int v = blockIdx.x * 256 + threadIdx.x;
  if (v < n) bias3[v] = b_vr[v] + tmpl[v];
}

// sum 8 vin split-K partials + bias2 + PE -> x (f32 + planes)
__global__ __launch_bounds__(256) void reduce_pe(const float* __restrict__ part,
                                                 const float* __restrict__ bias2,
                                                 float* __restrict__ x,
                                                 ushort_t* __restrict__ xh, ushort_t* __restrict__ xl) {
  const int t = blockIdx.x;
  const float PECOEF = -9.210340371976184f / 512.f;  // -ln(10000)/512
  const int p = t % 25;
  for (int d = threadIdx.x; d < 1024; d += 256) {
    float s = bias2[d];
    #pragma unroll
    for (int z = 0; z < 8; ++z) s += part[(size_t)z * 524288 + (size_t)t * 1024 + d];
    float arg = (float)p * expf((float)(d >> 1) * PECOEF);
    s += (d & 1) ? cosf(arg) : sinf(arg);
    const size_t idx = (size_t)t * 1024 + d;
    x[idx] = s;
    ushort_t h = f2bf(s);
    xh[idx] = h; xl[idx] = f2bf(s - bf2f(h));
  }
}

// V transpose + split: vT[h*256+d][s] planes from qkvf32[s][2048 + h*256 + d]
__global__ __launch_bounds__(256) void vT_split(const float* __restrict__ qkvf,
                                                ushort_t* __restrict__ vth, ushort_t* __restrict__ vtl) {
  __shared__ float tile[32][33];
  const int s0 = blockIdx.x * 32, d0 = blockIdx.y * 32;
  const int tx = threadIdx.x & 31, ty = threadIdx.x >> 5;  // 32 x 8
  for (int r = ty; r < 32; r += 8)
    tile[r][tx] = qkvf[(size_t)(s0 + r) * 3072 + 2048 + d0 + tx];
  __syncthreads();
  for (int r = ty; r < 32; r += 8) {
    float v = tile[tx][r];
    ushort_t h = f2bf(v);
    const size_t idx = (size_t)(d0 + r) * 512 + s0 + tx;
    vth[idx] = h; vtl[idx] = f2bf(v - bf2f(h));
  }
}

// row softmax with ALIBI + causal; reads raw scores f32, writes attn PLANES
__global__ __launch_bounds__(256) void softmax_alibi(const float* __restrict__ scores,
                                                     ushort_t* __restrict__ ah, ushort_t* __restrict__ al) {
  const int i = blockIdx.x, h = blockIdx.y;
  const size_t rb = ((size_t)h * 512 + i) * 512;
  const float* row = scores + rb;
  const int tid = threadIdx.x;
  const int len = i + 1;
  const float sl = exp2f(-2.f * (float)(h + 1));
  const int j0 = tid, j1 = tid + 256;
  float v0 = -INFINITY, v1 = -INFINITY;
  if (j0 < len) v0 = row[j0] * 0.0625f - sl * (float)((i - j0) / 25);
  if (j1 < len) v1 = row[j1] * 0.0625f - sl * (float)((i - j1) / 25);
  __shared__ float red[4];
  float m = blockReduceMax256(fmaxf(v0, v1), red);
  float e0 = (j0 < len) ? expf(v0 - m) : 0.f;
  float e1 = (j1 < len) ? expf(v1 - m) : 0.f;
  float s = blockReduceSum256(e0 + e1, red);
  float inv = 1.f / s;
  e0 *= inv; e1 *= inv;
  ushort_t h0 = f2bf(e0), h1 = f2bf(e1);
  ah[rb + j0] = h0; al[rb + j0] = f2bf(e0 - bf2f(h0));
  ah[rb + j1] = h1; al[rb + j1] = f2bf(e1 - bf2f(h1));
}

// x = LN(x + t)*g + b ; emits f32 + planes
__global__ __launch_bounds__(256) void ln_residual(float* __restrict__ x, const float* __restrict__ t_,
                                                   const float* __restrict__ g, const float* __restrict__ b,
                                                   ushort_t* __restrict__ xh, ushort_t* __restrict__ xl) {
  const int t = blockIdx.x, tid = threadIdx.x;
  float4 y = ((const float4*)(x + (size_t)t * 1024))[tid];
  float4 z = ((const float4*)(t_ + (size_t)t * 1024))[tid];
  y.x += z.x; y.y += z.y; y.z += z.z; y.w += z.w;
  __shared__ float red[4];
  float s = blockReduceSum256(y.x + y.y + y.z + y.w, red);
  const float m = s * (1.f / 1024.f);
  float dx = y.x - m, dy = y.y - m, dz = y.z - m, dw = y.w - m;
  float q = blockReduceSum256(dx * dx + dy * dy + dz * dz + dw * dw, red);
  const float rs = rsqrtf(q * (1.f / 1024.f) + 1e-5f);
  float4 gg = ((const float4*)g)[tid], bb = ((const float4*)b)[tid];
  float4 o;
  o.x = dx * rs * gg.x + bb.x;
  o.y = dy * rs * gg.y + bb.y;
  o.z = dz * rs * gg.z + bb.z;
  o.w = dw * rs * gg.w + bb.w;
  ((float4*)(x + (size_t)t * 1024))[tid] = o;
  ushort_t h0 = f2bf(o.x), h1 = f2bf(o.y), h2 = f2bf(o.z), h3 = f2bf(o.w);
  const int vi = t * 256 + tid;
  ((ushort4*)xh)[vi] = make_ushort4(h0, h1, h2, h3);
  ((ushort4*)xl)[vi] = make_ushort4(f2bf(o.x - bf2f(h0)), f2bf(o.y - bf2f(h1)),
                                    f2bf(o.z - bf2f(h2)), f2bf(o.w - bf2f(h3)));
}

// ---------------- host-side launch ----------------
extern "C" void kernel_launch(void* const* d_in, const int* in_sizes, int n_in,
                              void* d_out, int out_size, void* d_ws, size_t ws_size,
                              hipStream_t stream) {
  const float* audio   = (const float*)d_in[0];
  const float* vertice = (const float*)d_in[1];
  const float* tmpl    = (const float*)d_in[2];
  const float* one_hot = (const float*)d_in[3];
  const float* W_af    = (const float*)d_in[4];
  const float* b_af    = (const float*)d_in[5];
  const float* W_vm    = (const float*)d_in[6];
  const float* b_vm    = (const float*)d_in[7];
  const float* W_obj   = (const float*)d_in[8];
  const float* Wqkv_sa = (const float*)d_in[9];
  const float* bqkv_sa = (const float*)d_in[10];
  const float* Wo_sa   = (const float*)d_in[11];
  const float* bo_sa   = (const float*)d_in[12];
  const float* Wqkv_ca = (const float*)d_in[13];
  const float* bqkv_ca = (const float*)d_in[14];
  const float* Wo_ca   = (const float*)d_in[15];
  const float* bo_ca   = (const float*)d_in[16];
  const float* W1      = (const float*)d_in[17];
  const float* b1      = (const float*)d_in[18];
  const float* W2      = (const float*)d_in[19];
  const float* b2      = (const float*)d_in[20];
  const float* g1      = (const float*)d_in[21];
  const float* be1     = (const float*)d_in[22];
  const float* g2      = (const float*)d_in[23];
  const float* be2     = (const float*)d_in[24];
  const float* g3      = (const float*)d_in[25];
  const float* be3     = (const float*)d_in[26];
  const float* W_vr    = (const float*)d_in[27];
  const float* b_vr    = (const float*)d_in[28];
  float* out = (float*)d_out;

  // ---- workspace carve (floats), total ~109.6 MB ----
  float* base = (float*)d_ws;
  float*    bigW    = base;                  // 7,733,248 fl: Wvm-hi (1024x15104 us) then Wvr-hi (15069x1024 us)
  float*    apReg   = base + 7733248;        // 7,733,248 fl
  float*    part1   = apReg + 7733248;       // 4,194,304 fl
  float*    slotF   = part1 + 4194304;       // 3,145,728 fl (JIT weight planes)
  float*    x       = slotF + 3145728;       // 524,288
  float*    xpl     = x + 524288;            // 524,288 (xh | xl)
  float*    tmp     = xpl + 524288;          // 524,288
  float*    audpl   = tmp + 524288;          // 393,216
  float*    hidpl   = audpl + 393216;        // 524,288
  float*    ctxpl   = hidpl + 524288;        // 524,288
  float*    cvpl    = ctxpl + 524288;        // 524,288
  float*    h1pl    = cvpl + 524288;         // 1,048,576
  float*    bias2   = h1pl + 1048576;        // 1,024
  float*    bias3   = bias2 + 1024;          // 15,072

  ushort_t* bigWh = (ushort_t*)bigW;
  ushort_t* Aph   = (ushort_t*)apReg;            // 512*15104
  ushort_t* Apl   = Aph + 7733248;
  ushort_t* sloth = (ushort_t*)slotF;
  ushort_t* xh    = (ushort_t*)xpl;  ushort_t* xl  = xh + 524288;
  ushort_t* audh  = (ushort_t*)audpl; ushort_t* audl = audh + 393216;
  ushort_t* hidh  = (ushort_t*)hidpl; ushort_t* hidl = hidh + 524288;
  ushort_t* ctxh  = (ushort_t*)ctxpl; ushort_t* ctxl = ctxh + 524288;
  ushort_t* cvh   = (ushort_t*)cvpl;  ushort_t* cvl  = cvh + 524288;
  ushort_t* h1h   = (ushort_t*)h1pl;  ushort_t* h1l  = h1h + 1048576;

  // part1 aliases during attention: qkvf32 | qkv planes | scores
  float*    qkvf   = part1;                       // 1,572,864 fl
  ushort_t* qkvh   = (ushort_t*)(part1 + 1572864); // 1,572,864 us
  ushort_t* qkvl   = qkvh + 1572864;
  float*    scores = part1 + 3145728;             // 1,048,576 fl
  // apReg aliases after qkv partials are combined: attn planes | vT planes | ctx f32
  ushort_t* attnh  = (ushort_t*)apReg;            // 1,048,576 us
  ushort_t* attnl  = attnh + 1048576;
  ushort_t* vth    = attnl + 1048576;             // 524,288 us
  ushort_t* vtl    = vth + 524288;
  float*    ctxa   = apReg + 2097152 / 2 + 524288; // = apReg + 1572864 (fl)

  // ---- prep ----
  prep_bias2<<<4, 256, 0, stream>>>(one_hot, W_obj, b_vm, bias2);
  prep_bias3<<<(15069 + 255) / 256, 256, 0, stream>>>(b_vr, tmpl, bias3, 15069);
  prep_vin<<<512, 256, 0, stream>>>(vertice, tmpl, Aph, Apl);
  split_pad<false><<<1024, 256, 0, stream>>>(W_vm, bigWh, nullptr, 15069, KVIN);

  // ---- vin = Ap @ Wvm^T  (2-pass, split-K x8) -> part1 ----
  gsplit<2, false, false><<<dim3(8, 4, 8), 256, 0, stream>>>(
      Aph, Apl, bigWh, nullptr, nullptr, part1,
      1024, KVIN, KVIN, KVIN, 1024, 1888, 0, 0, 524288);
  reduce_pe<<<512, 256, 0, stream>>>(part1, bias2, x, xh, xl);

  // Wvr planes (reuse bigW; Wvm dead)
  split_pad<false><<<15069, 256, 0, stream>>>(W_vr, bigWh, nullptr, 1024, 1024);

  // ---- hidden = audio @ W_af^T + b_af ----
  split_pad<true><<<512, 256, 0, stream>>>(audio, audh, audl, 768, 768);
  split_pad<true><<<1024, 256, 0, stream>>>(W_af, sloth, sloth + 1024 * 768, 768, 768);
  gsplit<3, false, false><<<dim3(8, 4, 6), 256, 0, stream>>>(
      audh, audl, sloth, sloth + 1024 * 768, nullptr, part1,
      1024, 768, 768, 768, 1024, 128, 0, 0, 524288);
  combine<false, false, true><<<512, 256, 0, stream>>>(
      part1, b_af, nullptr, hidh, hidl, 6, 524288, 131072, 256);

  // ---- self attention ----
  split_pad<true><<<3072, 256, 0, stream>>>(Wqkv_sa, sloth, sloth + 3072 * 1024, 1024, 1024);
  gsplit<3, false, false><<<dim3(24, 4, 4), 256, 0, stream>>>(
      xh, xl, sloth, sloth + 3072 * 1024, nullptr, (float*)apReg,
      3072, 1024, 1024, 1024, 3072, 256, 0, 0, 1572864);
  combine<false, true, true><<<1536, 256, 0, stream>>>(
      (float*)apReg, bqkv_sa, qkvf, qkvh, qkvl, 4, 1572864, 393216, 768);
  vT_split<<<dim3(16, 32), 256, 0, stream>>>(qkvf, vth, vtl);
  // scores[h] = q_h @ k_h^T : z = head via kChunk=256
  gsplit<3, false, true><<<dim3(4, 4, 4), 256, 0, stream>>>(
      qkvh, qkvl, qkvh + 1024, qkvl + 1024, nullptr, scores,
      512, 1024, 3072, 3072, 512, 256, 0, 0, 262144);
  softmax_alibi<<<dim3(512, 4), 256, 0, stream>>>(scores, attnh, attnl);
  // ctx[h] = attn_h @ vT_h^T : z = head via aZ/bZ/cZ
  gsplit<3, false, false><<<dim3(2, 4, 4), 256, 0, stream>>>(
      attnh, attnl, vth, vtl, nullptr, ctxa,
      256, 512, 512, 512, 1024, 0, 262144, 131072, 256);
  split_pad<true><<<512, 256, 0, stream>>>(ctxa, ctxh, ctxl, 1024, 1024);
  // out proj
  split_pad<true><<<1024, 256, 0, stream>>>(Wo_sa, sloth, sloth + 1024 * 1024, 1024, 1024);
  gsplit<3, false, false><<<dim3(8, 4, 8), 256, 0, stream>>>(
      ctxh, ctxl, sloth, sloth + 1024 * 1024, nullptr, part1,
      1024, 1024, 1024, 1024, 1024, 128, 0, 0, 524288);
  combine<false, true, false><<<512, 256, 0, stream>>>(
      part1, bo_sa, tmp, nullptr, nullptr, 8, 524288, 131072, 256);
  ln_residual<<<512, 256, 0, stream>>>(x, tmp, g1, be1, xh, xl);

  // ---- cross attention: bool mask == identity -> V then O projection ----
  split_pad<true><<<1024, 256, 0, stream>>>(Wqkv_ca + (size_t)2048 * 1024, sloth, sloth + 1024 * 1024, 1024, 1024);
  gsplit<3, false, false><<<dim3(8, 4, 8), 256, 0, stream>>>(
      hidh, hidl, sloth, sloth + 1024 * 1024, nullptr, part1,
      1024, 1024, 1024, 1024, 1024, 128, 0, 0, 524288);
  combine<false, false, true><<<512, 256, 0, stream>>>(
      part1, bqkv_ca + 2048, nullptr, cvh, cvl, 8, 524288, 131072, 256);
  split_pad<true><<<1024, 256, 0, stream>>>(Wo_ca, sloth, sloth + 1024 * 1024, 1024, 1024);
  gsplit<3, false, false><<<dim3(8, 4, 8), 256, 0, stream>>>(
      cvh, cvl, sloth, sloth + 1024 * 1024, nullptr, part1,
      1024, 1024, 1024, 1024, 1024, 128, 0, 0, 524288);
  combine<false, true, false><<<512, 256, 0, stream>>>(
      part1, bo_ca, tmp, nullptr, nullptr, 8, 524288, 131072, 256);
  ln_residual<<<512, 256, 0, stream>>>(x, tmp, g2, be2, xh, xl);

  // ---- feed forward ----
  split_pad<true><<<2048, 256, 0, stream>>>(W1, sloth, sloth + 2048 * 1024, 1024, 1024);
  gsplit<3, false, false><<<dim3(16, 4, 4), 256, 0, stream>>>(
      xh, xl, sloth, sloth + 2048 * 1024, nullptr, part1,
      2048, 1024, 1024, 1024, 2048, 256, 0, 0, 1048576);
  combine<true, false, true><<<1024, 256, 0, stream>>>(
      part1, b1, nullptr, h1h, h1l, 4, 1048576, 262144, 512);
  split_pad<true><<<1024, 256, 0, stream>>>(W2, sloth, sloth + 1024 * 2048, 2048, 2048);
  gsplit<3, false, false><<<dim3(8, 4, 8), 256, 0, stream>>>(
      h1h, h1l, sloth, sloth + 1024 * 2048, nullptr, part1,
      1024, 2048, 2048, 2048, 1024, 256, 0, 0, 524288);
  combine<false, true, false><<<512, 256, 0, stream>>>(
      part1, b2, tmp, nullptr, nullptr, 8, 524288, 131072, 256);
  ln_residual<<<512, 256, 0, stream>>>(x, tmp, g3, be3, xh, xl);

  // ---- final projection: out = x @ W_vr^T + (b_vr + tmpl)  (2-pass) ----
  gsplit<2, true, false><<<dim3(118, 4, 1), 256, 0, stream>>>(
      xh, xl, bigWh, nullptr, bias3, out,
      15069, 1024, 1024, 1024, 15069, 0, 0, 0, 0);
}

// Round 5
// 396.394 us; speedup vs baseline: 4.0091x; 1.1091x over previous
//
#include <hip/hip_runtime.h>
#include <math.h>

typedef __attribute__((ext_vector_type(8))) short short8;
typedef __attribute__((ext_vector_type(4))) float f32x4;
typedef unsigned short ushort_t;

#define LDK 40      // padded LDS row (bf16 elems): 80B stride -> max 2-way bank conflict (free)
#define KVIN 15104  // 15069 padded to multiple of 32

__device__ __forceinline__ ushort_t f2bf(float f) {
  unsigned u = __float_as_uint(f);
  return (ushort_t)((u + 0x7fffu + ((u >> 16) & 1u)) >> 16);  // RNE
}
__device__ __forceinline__ float bf2f(ushort_t h) {
  return __uint_as_float(((unsigned)h) << 16);
}

// ---------------- block reduction helpers (256-thread blocks) ----------------
__device__ __forceinline__ float blockReduceSum256(float v, float* red) {
  #pragma unroll
  for (int o = 32; o; o >>= 1) v += __shfl_xor(v, o);
  int wid = threadIdx.x >> 6, lane = threadIdx.x & 63;
  if (lane == 0) red[wid] = v;
  __syncthreads();
  v = red[0] + red[1] + red[2] + red[3];
  __syncthreads();
  return v;
}
__device__ __forceinline__ float blockReduceMax256(float v, float* red) {
  #pragma unroll
  for (int o = 32; o; o >>= 1) v = fmaxf(v, __shfl_xor(v, o));
  int wid = threadIdx.x >> 6, lane = threadIdx.x & 63;
  if (lane == 0) red[wid] = v;
  __syncthreads();
  v = fmaxf(fmaxf(red[0], red[1]), fmaxf(red[2], red[3]));
  __syncthreads();
  return v;
}

// ============ 2-pass bf16 MFMA GEMM, 64x128 tile: C = A @ B^T (+bias) ============
// A as hi/lo planes, B hi plane only.  acc += Ah*Bh + Al*Bh  (drops Ah*Bl, 2^-9 rel).
// M % 64 == 0 via grid.y. N ragged. kChunk>0: split-K via z (kChunk%32==0).
// aZ/bZ/cZ: per-z element offsets (head batching). POUT: write hi/lo planes to Ch/Cl.
template <bool BIAS, bool CAUSAL, bool POUT>
__global__ __launch_bounds__(256, 2) void gsplit64(
    const ushort_t* __restrict__ Ah, const ushort_t* __restrict__ Al,
    const ushort_t* __restrict__ Bh,
    const float* __restrict__ bias, float* __restrict__ C,
    ushort_t* __restrict__ Ch, ushort_t* __restrict__ Cl,
    int N, int K, int lda, int ldb, int ldc,
    int kChunk, long aZ, long bZ, long cZ)
{
  const int m0 = blockIdx.y * 64, n0 = blockIdx.x * 128;
  if (CAUSAL && n0 > m0 + 63) return;
  __shared__ ushort_t sAh[64 * LDK], sAl[64 * LDK], sBh[128 * LDK];
  const int tid = threadIdx.x, z = blockIdx.z;
  const int kBeg = kChunk ? z * kChunk : 0;
  const int kEnd = kChunk ? kBeg + kChunk : K;
  Ah += (size_t)z * aZ; Al += (size_t)z * aZ; Bh += (size_t)z * bZ;
  C  += (size_t)z * cZ;
  if (POUT) { Ch += (size_t)z * cZ; Cl += (size_t)z * cZ; }

  // A staging: 64 rows x 4 threads (8 k each)
  const int arow = tid >> 2, akc = (tid & 3) << 3;
  const ushort_t* pAh = Ah + (size_t)(m0 + arow) * lda + akc;
  const ushort_t* pAl = Al + (size_t)(m0 + arow) * lda + akc;
  // B staging: 128 rows x 2 threads (16 k each)
  const int brow = tid >> 1, bkc = (tid & 1) << 4;
  const int gbn = n0 + brow;
  const bool bok = gbn < N;
  const ushort_t* pB = Bh + (size_t)gbn * ldb + bkc;

  // 4 waves side by side along N: each computes 64x32
  const int lane = tid & 63;
  const int wc = (tid >> 6) << 5;       // 0,32,64,96
  const int fr = lane & 15, fq = lane >> 4;

  f32x4 acc[4][2] = {};
  const short8 z8 = {0, 0, 0, 0, 0, 0, 0, 0};
  short8 rah, ral, rb0, rb1;

  rah = *(const short8*)(pAh + kBeg);
  ral = *(const short8*)(pAl + kBeg);
  rb0 = bok ? *(const short8*)(pB + kBeg) : z8;
  rb1 = bok ? *(const short8*)(pB + kBeg + 8) : z8;

  for (int k0 = kBeg; k0 < kEnd; k0 += 32) {
    __syncthreads();  // prior iter's fragment reads complete
    *(short8*)&sAh[arow * LDK + akc] = rah;
    *(short8*)&sAl[arow * LDK + akc] = ral;
    *(short8*)&sBh[brow * LDK + bkc] = rb0;
    *(short8*)&sBh[brow * LDK + bkc + 8] = rb1;
    if (k0 + 32 < kEnd) {  // prefetch next k-step
      const int k = k0 + 32;
      rah = *(const short8*)(pAh + k);
      ral = *(const short8*)(pAl + k);
      rb0 = bok ? *(const short8*)(pB + k) : z8;
      rb1 = bok ? *(const short8*)(pB + k + 8) : z8;
    }
    __syncthreads();  // writes visible

    short8 fah[4], fal[4];
    #pragma unroll
    for (int f = 0; f < 4; ++f) {
      const int r = (f * 16 + fr) * LDK + fq * 8;
      fah[f] = *(const short8*)&sAh[r];
      fal[f] = *(const short8*)&sAl[r];
    }
    #pragma unroll
    for (int g = 0; g < 2; ++g) {
      short8 fb = *(const short8*)&sBh[(wc + g * 16 + fr) * LDK + fq * 8];
      #pragma unroll
      for (int f = 0; f < 4; ++f) {
        acc[f][g] = __builtin_amdgcn_mfma_f32_16x16x32_bf16(fah[f], fb, acc[f][g], 0, 0, 0);
        acc[f][g] = __builtin_amdgcn_mfma_f32_16x16x32_bf16(fal[f], fb, acc[f][g], 0, 0, 0);
      }
    }
  }

  // epilogue: C/D layout col=lane&15, row=(lane>>4)*4+reg
  #pragma unroll
  for (int f = 0; f < 4; ++f) {
    const int gm = m0 + f * 16 + fq * 4;
    #pragma unroll
    for (int g = 0; g < 2; ++g) {
      const int gn = n0 + wc + g * 16 + fr;
      if (gn < N) {
        #pragma unroll
        for (int i = 0; i < 4; ++i) {
          float v = acc[f][g][i];
          if (BIAS) v += bias[gn];
          const size_t o = (size_t)(gm + i) * ldc + gn;
          if (POUT) {
            ushort_t h = f2bf(v);
            Ch[o] = h; Cl[o] = f2bf(v - bf2f(h));
          } else {
            C[o] = v;
          }
        }
      }
    }
  }
}

// ============ 2-pass bf16 MFMA GEMM, 128x128 tile (final projection) ============
template <bool BIAS>
__global__ __launch_bounds__(256, 2) void gsplit128(
    const ushort_t* __restrict__ Ah, const ushort_t* __restrict__ Al,
    const ushort_t* __restrict__ Bh,
    const float* __restrict__ bias, float* __restrict__ C,
    int N, int K, int lda, int ldb, int ldc)
{
  __shared__ ushort_t sAh[128 * LDK], sAl[128 * LDK], sBh[128 * LDK];
  const int tid = threadIdx.x;
  const int m0 = blockIdx.y * 128, n0 = blockIdx.x * 128;

  const int srow = tid >> 1, skc = (tid & 1) << 4;
  const ushort_t* pAh = Ah + (size_t)(m0 + srow) * lda + skc;
  const ushort_t* pAl = Al + (size_t)(m0 + srow) * lda + skc;
  const int gbn = n0 + srow;
  const bool bok = gbn < N;
  const ushort_t* pB = Bh + (size_t)gbn * ldb + skc;

  const int lane = tid & 63;
  const int wr = ((tid >> 7) & 1) << 6;
  const int wc = ((tid >> 6) & 1) << 6;
  const int fr = lane & 15, fq = lane >> 4;

  f32x4 acc[4][4] = {};
  const short8 z8 = {0, 0, 0, 0, 0, 0, 0, 0};
  short8 rah0, rah1, ral0, ral1, rb0, rb1;

  rah0 = *(const short8*)(pAh);     rah1 = *(const short8*)(pAh + 8);
  ral0 = *(const short8*)(pAl);     ral1 = *(const short8*)(pAl + 8);
  rb0 = bok ? *(const short8*)(pB) : z8;
  rb1 = bok ? *(const short8*)(pB + 8) : z8;

  for (int k0 = 0; k0 < K; k0 += 32) {
    __syncthreads();
    const int wb = srow * LDK + skc;
    *(short8*)&sAh[wb] = rah0; *(short8*)&sAh[wb + 8] = rah1;
    *(short8*)&sAl[wb] = ral0; *(short8*)&sAl[wb + 8] = ral1;
    *(short8*)&sBh[wb] = rb0;  *(short8*)&sBh[wb + 8] = rb1;
    if (k0 + 32 < K) {
      const int k = k0 + 32;
      rah0 = *(const short8*)(pAh + k); rah1 = *(const short8*)(pAh + k + 8);
      ral0 = *(const short8*)(pAl + k); ral1 = *(const short8*)(pAl + k + 8);
      rb0 = bok ? *(const short8*)(pB + k) : z8;
      rb1 = bok ? *(const short8*)(pB + k + 8) : z8;
    }
    __syncthreads();

    short8 fah[4], fal[4];
    #pragma unroll
    for (int f = 0; f < 4; ++f) {
      const int r = (wr + f * 16 + fr) * LDK + fq * 8;
      fah[f] = *(const short8*)&sAh[r];
      fal[f] = *(const short8*)&sAl[r];
    }
    #pragma unroll
    for (int g = 0; g < 4; ++g) {
      short8 fb = *(const short8*)&sBh[(wc + g * 16 + fr) * LDK + fq * 8];
      #pragma unroll
      for (int f = 0; f < 4; ++f) {
        acc[f][g] = __builtin_amdgcn_mfma_f32_16x16x32_bf16(fah[f], fb, acc[f][g], 0, 0, 0);
        acc[f][g] = __builtin_amdgcn_mfma_f32_16x16x32_bf16(fal[f], fb, acc[f][g], 0, 0, 0);
      }
    }
  }

  #pragma unroll
  for (int f = 0; f < 4; ++f) {
    const int gm = m0 + wr + f * 16 + fq * 4;
    #pragma unroll
    for (int g = 0; g < 4; ++g) {
      const int gn = n0 + wc + g * 16 + fr;
      if (gn < N) {
        float* cp = C + (size_t)gm * ldc + gn;
        #pragma unroll
        for (int i = 0; i < 4; ++i) {
          float v = acc[f][g][i];
          if (BIAS) v += bias[gn];
          cp[(size_t)i * ldc] = v;
        }
      }
    }
  }
}

// ---------------- split-K combine: out = sum_z part[z] + bias (+relu) ----------------
template <bool RELU, bool F32OUT, bool PLANES>
__global__ __launch_bounds__(256) void combine(
    const float* __restrict__ part, const float* __restrict__ bias,
    float* __restrict__ outf, ushort_t* __restrict__ outh, ushort_t* __restrict__ outl,
    int nz, long zstride, int total4, int N4)
{
  const int i = blockIdx.x * 256 + threadIdx.x;
  if (i >= total4) return;
  float4 s = ((const float4*)bias)[i % N4];
  for (int z = 0; z < nz; ++z) {
    float4 p = ((const float4*)(part + (size_t)z * zstride))[i];
    s.x += p.x; s.y += p.y; s.z += p.z; s.w += p.w;
  }
  if (RELU) {
    s.x = fmaxf(s.x, 0.f); s.y = fmaxf(s.y, 0.f);
    s.z = fmaxf(s.z, 0.f); s.w = fmaxf(s.w, 0.f);
  }
  if (F32OUT) ((float4*)outf)[i] = s;
  if (PLANES) {
    ushort_t h0 = f2bf(s.x), h1 = f2bf(s.y), h2 = f2bf(s.z), h3 = f2bf(s.w);
    ((ushort4*)outh)[i] = make_ushort4(h0, h1, h2, h3);
    ((ushort4*)outl)[i] = make_ushort4(f2bf(s.x - bf2f(h0)), f2bf(s.y - bf2f(h1)),
                                       f2bf(s.z - bf2f(h2)), f2bf(s.w - bf2f(h3)));
  }
}

// ---------------- fp32 (R x Csrc) -> hi(/lo) planes (R x Cdst), zero-padded ----------------
template <bool LO>
__global__ __launch_bounds__(256) void split_pad(
    const float* __restrict__ src, ushort_t* __restrict__ dh, ushort_t* __restrict__ dl,
    int Csrc, int Cdst)
{
  const int r = blockIdx.x;
  for (int c = threadIdx.x; c < Cdst; c += 256) {
    float v = (c < Csrc) ? src[(size_t)r * Csrc + c] : 0.f;
    ushort_t h = f2bf(v);
    dh[(size_t)r * Cdst + c] = h;
    if (LO) dl[(size_t)r * Cdst + c] = f2bf(v - bf2f(h));
  }
}

// ---------------- vin input: planes of concat(0, vertice[:-1]) - tmpl ----------------
__global__ __launch_bounds__(256) void prep_vin(const float* __restrict__ vertice,
                                                const float* __restrict__ tmpl,
                                                ushort_t* __restrict__ dh, ushort_t* __restrict__ dl) {
  const int t = blockIdx.x;
  for (int k = threadIdx.x; k < KVIN; k += 256) {
    float v = 0.f;
    if (t > 0 && k < 15069) v = vertice[(size_t)(t - 1) * 15069 + k] - tmpl[k];
    ushort_t h = f2bf(v);
    dh[(size_t)t * KVIN + k] = h;
    dl[(size_t)t * KVIN + k] = f2bf(v - bf2f(h));
  }
}

__global__ void prep_bias2(const float* __restrict__ one_hot, const float* __restrict__ W_obj,
                           const float* __restrict__ b_vm, float* __restrict__ bias2) {
  int d = blockIdx.x * 256 + threadIdx.x;
  if (d < 1024) {
    float s = 0.f;
    #pragma unroll
    for (int j = 0; j < 8; ++j) s += one_hot[j] * W_obj[d * 8 + j];
    bias2[d] = b_vm[d] + s;
  }
}

__global__ void prep_bias3(const float* __restrict__ b_vr, const float* __restrict__ tmpl,
                           float* __restrict__ bias3, int n) {
  int v = blockIdx.x * 256 + threadIdx.x;
  if (v < n) bias3[v] = b_vr[v] + tmpl[v];
}

// sum 8 vin split-K partials + bias2 + PE -> x (f32 + planes)
__global__ __launch_bounds__(256) void reduce_pe(const float* __restrict__ part,
                                                 const float* __restrict__ bias2,
                                                 float* __restrict__ x,
                                                 ushort_t* __restrict__ xh, ushort_t* __restrict__ xl) {
  const int t = blockIdx.x;
  const float PECOEF = -9.210340371976184f / 512.f;  // -ln(10000)/512
  const int p = t % 25;
  for (int d = threadIdx.x; d < 1024; d += 256) {
    float s = bias2[d];
    #pragma unroll
    for (int z = 0; z < 8; ++z) s += part[(size_t)z * 524288 + (size_t)t * 1024 + d];
    float arg = (float)p * expf((float)(d >> 1) * PECOEF);
    s += (d & 1) ? cosf(arg) : sinf(arg);
    const size_t idx = (size_t)t * 1024 + d;
    x[idx] = s;
    ushort_t h = f2bf(s);
    xh[idx] = h; xl[idx] = f2bf(s - bf2f(h));
  }
}

// V transpose: vT[h*256+d][s] hi plane from qkvf32[s][2048 + h*256 + d]
__global__ __launch_bounds__(256) void vT_split(const float* __restrict__ qkvf,
                                                ushort_t* __restrict__ vth) {
  __shared__ float tile[32][33];
  const int s0 = blockIdx.x * 32, d0 = blockIdx.y * 32;
  const int tx = threadIdx.x & 31, ty = threadIdx.x >> 5;  // 32 x 8
  for (int r = ty; r < 32; r += 8)
    tile[r][tx] = qkvf[(size_t)(s0 + r) * 3072 + 2048 + d0 + tx];
  __syncthreads();
  for (int r = ty; r < 32; r += 8) {
    float v = tile[tx][r];
    vth[(size_t)(d0 + r) * 512 + s0 + tx] = f2bf(v);
  }
}

// row softmax with ALIBI + causal; reads raw scores f32, writes attn planes
__global__ __launch_bounds__(256) void softmax_alibi(const float* __restrict__ scores,
                                                     ushort_t* __restrict__ ah, ushort_t* __restrict__ al) {
  const int i = blockIdx.x, h = blockIdx.y;
  const size_t rb = ((size_t)h * 512 + i) * 512;
  const float* row = scores + rb;
  const int tid = threadIdx.x;
  const int len = i + 1;
  const float sl = exp2f(-2.f * (float)(h + 1));
  const int j0 = tid, j1 = tid + 256;
  float v0 = -INFINITY, v1 = -INFINITY;
  if (j0 < len) v0 = row[j0] * 0.0625f - sl * (float)((i - j0) / 25);
  if (j1 < len) v1 = row[j1] * 0.0625f - sl * (float)((i - j1) / 25);
  __shared__ float red[4];
  float m = blockReduceMax256(fmaxf(v0, v1), red);
  float e0 = (j0 < len) ? expf(v0 - m) : 0.f;
  float e1 = (j1 < len) ? expf(v1 - m) : 0.f;
  float s = blockReduceSum256(e0 + e1, red);
  float inv = 1.f / s;
  e0 *= inv; e1 *= inv;
  ushort_t h0 = f2bf(e0), h1 = f2bf(e1);
  ah[rb + j0] = h0; al[rb + j0] = f2bf(e0 - bf2f(h0));
  ah[rb + j1] = h1; al[rb + j1] = f2bf(e1 - bf2f(h1));
}

// x = LN(x + t)*g + b ; emits f32 + planes
__global__ __launch_bounds__(256) void ln_residual(float* __restrict__ x, const float* __restrict__ t_,
                                                   const float* __restrict__ g, const float* __restrict__ b,
                                                   ushort_t* __restrict__ xh, ushort_t* __restrict__ xl) {
  const int t = blockIdx.x, tid = threadIdx.x;
  float4 y = ((const float4*)(x + (size_t)t * 1024))[tid];
  float4 z = ((const float4*)(t_ + (size_t)t * 1024))[tid];
  y.x += z.x; y.y += z.y; y.z += z.z; y.w += z.w;
  __shared__ float red[4];
  float s = blockReduceSum256(y.x + y.y + y.z + y.w, red);
  const float m = s * (1.f / 1024.f);
  float dx = y.x - m, dy = y.y - m, dz = y.z - m, dw = y.w - m;
  float q = blockReduceSum256(dx * dx + dy * dy + dz * dz + dw * dw, red);
  const float rs = rsqrtf(q * (1.f / 1024.f) + 1e-5f);
  float4 gg = ((const float4*)g)[tid], bb = ((const float4*)b)[tid];
  float4 o;
  o.x = dx * rs * gg.x + bb.x;
  o.y = dy * rs * gg.y + bb.y;
  o.z = dz * rs * gg.z + bb.z;
  o.w = dw * rs * gg.w + bb.w;
  ((float4*)(x + (size_t)t * 1024))[tid] = o;
  ushort_t h0 = f2bf(o.x), h1 = f2bf(o.y), h2 = f2bf(o.z), h3 = f2bf(o.w);
  const int vi = t * 256 + tid;
  ((ushort4*)xh)[vi] = make_ushort4(h0, h1, h2, h3);
  ((ushort4*)xl)[vi] = make_ushort4(f2bf(o.x - bf2f(h0)), f2bf(o.y - bf2f(h1)),
                                    f2bf(o.z - bf2f(h2)), f2bf(o.w - bf2f(h3)));
}

// ---------------- host-side launch ----------------
extern "C" void kernel_launch(void* const* d_in, const int* in_sizes, int n_in,
                              void* d_out, int out_size, void* d_ws, size_t ws_size,
                              hipStream_t stream) {
  const float* audio   = (const float*)d_in[0];
  const float* vertice = (const float*)d_in[1];
  const float* tmpl    = (const float*)d_in[2];
  const float* one_hot = (const float*)d_in[3];
  const float* W_af    = (const float*)d_in[4];
  const float* b_af    = (const float*)d_in[5];
  const float* W_vm    = (const float*)d_in[6];
  const float* b_vm    = (const float*)d_in[7];
  const float* W_obj   = (const float*)d_in[8];
  const float* Wqkv_sa = (const float*)d_in[9];
  const float* bqkv_sa = (const float*)d_in[10];
  const float* Wo_sa   = (const float*)d_in[11];
  const float* bo_sa   = (const float*)d_in[12];
  const float* Wqkv_ca = (const float*)d_in[13];
  const float* bqkv_ca = (const float*)d_in[14];
  const float* Wo_ca   = (const float*)d_in[15];
  const float* bo_ca   = (const float*)d_in[16];
  const float* W1      = (const float*)d_in[17];
  const float* b1      = (const float*)d_in[18];
  const float* W2      = (const float*)d_in[19];
  const float* b2      = (const float*)d_in[20];
  const float* g1      = (const float*)d_in[21];
  const float* be1     = (const float*)d_in[22];
  const float* g2      = (const float*)d_in[23];
  const float* be2     = (const float*)d_in[24];
  const float* g3      = (const float*)d_in[25];
  const float* be3     = (const float*)d_in[26];
  const float* W_vr    = (const float*)d_in[27];
  const float* b_vr    = (const float*)d_in[28];
  float* out = (float*)d_out;

  // ---- workspace carve (floats), same footprint as round 4 (~110 MB) ----
  float* base = (float*)d_ws;
  float*    bigW    = base;                  // 7,733,248 fl: Wvm-hi then Wvr-hi (us)
  float*    apReg   = base + 7733248;        // 7,733,248 fl
  float*    part1   = apReg + 7733248;       // 4,194,304 fl
  float*    slotF   = part1 + 4194304;       // 3,145,728 fl (JIT weight hi planes)
  float*    x       = slotF + 3145728;       // 524,288
  float*    xpl     = x + 524288;            // 524,288 (xh | xl)
  float*    tmp     = xpl + 524288;          // 524,288
  float*    audpl   = tmp + 524288;          // 393,216
  float*    hidpl   = audpl + 393216;        // 524,288
  float*    ctxpl   = hidpl + 524288;        // 524,288
  float*    cvpl    = ctxpl + 524288;        // 524,288
  float*    h1pl    = cvpl + 524288;         // 1,048,576
  float*    bias2   = h1pl + 1048576;        // 1,024
  float*    bias3   = bias2 + 1024;          // 15,072

  ushort_t* bigWh = (ushort_t*)bigW;
  ushort_t* Aph   = (ushort_t*)apReg;             // 512*15104
  ushort_t* Apl   = Aph + 7733248;
  ushort_t* sloth = (ushort_t*)slotF;
  ushort_t* xh    = (ushort_t*)xpl;   ushort_t* xl   = xh + 524288;
  ushort_t* audh  = (ushort_t*)audpl; ushort_t* audl = audh + 393216;
  ushort_t* hidh  = (ushort_t*)hidpl; ushort_t* hidl = hidh + 524288;
  ushort_t* ctxh  = (ushort_t*)ctxpl; ushort_t* ctxl = ctxh + 524288;
  ushort_t* cvh   = (ushort_t*)cvpl;  ushort_t* cvl  = cvh + 524288;
  ushort_t* h1h   = (ushort_t*)h1pl;  ushort_t* h1l  = h1h + 1048576;

  // part1 aliases during attention: qkvf32 | qkv planes | scores
  float*    qkvf   = part1;                        // 1,572,864 fl
  ushort_t* qkvh   = (ushort_t*)(part1 + 1572864); // 1,572,864 us
  ushort_t* qkvl   = qkvh + 1572864;
  float*    scores = part1 + 3145728;              // 1,048,576 fl
  // apReg aliases after vin (Ap dead): qkv partials, then attn planes | vT hi
  ushort_t* attnh  = (ushort_t*)apReg;             // 1,048,576 us
  ushort_t* attnl  = attnh + 1048576;
  ushort_t* vth    = attnl + 1048576;              // 524,288 us

  // ---- prep ----
  prep_bias2<<<4, 256, 0, stream>>>(one_hot, W_obj, b_vm, bias2);
  prep_bias3<<<(15069 + 255) / 256, 256, 0, stream>>>(b_vr, tmpl, bias3, 15069);
  prep_vin<<<512, 256, 0, stream>>>(vertice, tmpl, Aph, Apl);
  split_pad<false><<<1024, 256, 0, stream>>>(W_vm, bigWh, nullptr, 15069, KVIN);

  // ---- vin = Ap @ Wvm^T  (split-K x8, 64x128 tiles -> 512 blocks) ----
  gsplit64<false, false, false><<<dim3(8, 8, 8), 256, 0, stream>>>(
      Aph, Apl, bigWh, nullptr, part1, nullptr, nullptr,
      1024, KVIN, KVIN, KVIN, 1024, 1888, 0, 0, 524288);
  reduce_pe<<<512, 256, 0, stream>>>(part1, bias2, x, xh, xl);

  // Wvr hi plane (reuse bigW; Wvm dead)
  split_pad<false><<<15069, 256, 0, stream>>>(W_vr, bigWh, nullptr, 1024, 1024);

  // ---- hidden = audio @ W_af^T + b_af ----
  split_pad<true><<<512, 256, 0, stream>>>(audio, audh, audl, 768, 768);
  split_pad<false><<<1024, 256, 0, stream>>>(W_af, sloth, nullptr, 768, 768);
  gsplit64<false, false, false><<<dim3(8, 8, 6), 256, 0, stream>>>(
      audh, audl, sloth, nullptr, part1, nullptr, nullptr,
      1024, 768, 768, 768, 1024, 128, 0, 0, 524288);
  combine<false, false, true><<<512, 256, 0, stream>>>(
      part1, b_af, nullptr, hidh, hidl, 6, 524288, 131072, 256);

  // ---- self attention ----
  split_pad<false><<<3072, 256, 0, stream>>>(Wqkv_sa, sloth, nullptr, 1024, 1024);
  gsplit64<false, false, false><<<dim3(24, 8, 4), 256, 0, stream>>>(
      xh, xl, sloth, nullptr, (float*)apReg, nullptr, nullptr,
      3072, 1024, 1024, 1024, 3072, 256, 0, 0, 1572864);
  combine<false, true, true><<<1536, 256, 0, stream>>>(
      (float*)apReg, bqkv_sa, qkvf, qkvh, qkvl, 4, 1572864, 393216, 768);
  vT_split<<<dim3(16, 32), 256, 0, stream>>>(qkvf, vth);
  // scores[h] = q_h @ k_h^T : z = head via kChunk=256 (causal tiles only)
  gsplit64<false, true, false><<<dim3(4, 8, 4), 256, 0, stream>>>(
      qkvh, qkvl, qkvh + 1024, nullptr, scores, nullptr, nullptr,
      512, 1024, 3072, 3072, 512, 256, 0, 0, 262144);
  softmax_alibi<<<dim3(512, 4), 256, 0, stream>>>(scores, attnh, attnl);
  // ctx[h] = attn_h @ vT_h^T, planes out directly
  gsplit64<false, false, true><<<dim3(2, 8, 4), 256, 0, stream>>>(
      attnh, attnl, vth, nullptr, nullptr, ctxh, ctxl,
      256, 512, 512, 512, 1024, 0, 262144, 131072, 256);
  // out proj
  split_pad<false><<<1024, 256, 0, stream>>>(Wo_sa, sloth, nullptr, 1024, 1024);
  gsplit64<false, false, false><<<dim3(8, 8, 8), 256, 0, stream>>>(
      ctxh, ctxl, sloth, nullptr, part1, nullptr, nullptr,
      1024, 1024, 1024, 1024, 1024, 128, 0, 0, 524288);
  combine<false, true, false><<<512, 256, 0, stream>>>(
      part1, bo_sa, tmp, nullptr, nullptr, 8, 524288, 131072, 256);
  ln_residual<<<512, 256, 0, stream>>>(x, tmp, g1, be1, xh, xl);

  // ---- cross attention: bool mask == identity -> V then O projection ----
  split_pad<false><<<1024, 256, 0, stream>>>(Wqkv_ca + (size_t)2048 * 1024, sloth, nullptr, 1024, 1024);
  gsplit64<false, false, false><<<dim3(8, 8, 8), 256, 0, stream>>>(
      hidh, hidl, sloth, nullptr, part1, nullptr, nullptr,
      1024, 1024, 1024, 1024, 1024, 128, 0, 0, 524288);
  combine<false, false, true><<<512, 256, 0, stream>>>(
      part1, bqkv_ca + 2048, nullptr, cvh, cvl, 8, 524288, 131072, 256);
  split_pad<false><<<1024, 256, 0, stream>>>(Wo_ca, sloth, nullptr, 1024, 1024);
  gsplit64<false, false, false><<<dim3(8, 8, 8), 256, 0, stream>>>(
      cvh, cvl, sloth, nullptr, part1, nullptr, nullptr,
      1024, 1024, 1024, 1024, 1024, 128, 0, 0, 524288);
  combine<false, true, false><<<512, 256, 0, stream>>>(
      part1, bo_ca, tmp, nullptr, nullptr, 8, 524288, 131072, 256);
  ln_residual<<<512, 256, 0, stream>>>(x, tmp, g2, be2, xh, xl);

  // ---- feed forward ----
  split_pad<false><<<2048, 256, 0, stream>>>(W1, sloth, nullptr, 1024, 1024);
  gsplit64<false, false, false><<<dim3(16, 8, 4), 256, 0, stream>>>(
      xh, xl, sloth, nullptr, part1, nullptr, nullptr,
      2048, 1024, 1024, 1024, 2048, 256, 0, 0, 1048576);
  combine<true, false, true><<<1024, 256, 0, stream>>>(
      part1, b1, nullptr, h1h, h1l, 4, 1048576, 262144, 512);
  split_pad<false><<<1024, 256, 0, stream>>>(W2, sloth, nullptr, 2048, 2048);
  gsplit64<false, false, false><<<dim3(8, 8, 8), 256, 0, stream>>>(
      h1h, h1l, sloth, nullptr, part1, nullptr, nullptr,
      1024, 2048, 2048, 2048, 1024, 256, 0, 0, 524288);
  combine<false, true, false><<<512, 256, 0, stream>>>(
      part1, b2, tmp, nullptr, nullptr, 8, 524288, 131072, 256);
  ln_residual<<<512, 256, 0, stream>>>(x, tmp, g3, be3, xh, xl);

  // ---- final projection: out = x @ W_vr^T + (b_vr + tmpl)  (128x128 tiles) ----
  gsplit128<true><<<dim3(118, 4), 256, 0, stream>>>(
      xh, xl, bigWh, bias3, out, 15069, 1024, 1024, 1024, 15069);
}